// Round 12
// baseline (230.320 us; speedup 1.0000x reference)
//
#include <hip/hip_runtime.h>

typedef __attribute__((ext_vector_type(8))) short bf16x8;
typedef __attribute__((ext_vector_type(4))) short short4v;
typedef __attribute__((ext_vector_type(4))) float f32x4;

// B=128, N=256, D=256, H=4 ; per-batch matrices are [256][256] (65536 elems)

__device__ __forceinline__ float b2f(short s){
  unsigned u = ((unsigned)(unsigned short)s) << 16;
  return __builtin_bit_cast(float, u);
}
__device__ __forceinline__ short f2b(float f){
  unsigned u = __builtin_bit_cast(unsigned, f);
  u = (u + 0x7FFFu + ((u >> 16) & 1u)) >> 16;
  return (short)(unsigned short)u;
}

// XOR swizzle for 512B-stride rows: spread across the 8 16B-slot orbit.
#define SWZ(row, bytecol) ((((row) * 512) + (bytecol)) ^ (((row) & 7) << 4))

// -------- transpose-convert f32 [256][256] -> bf16 ^T : z=0 fc_w->WT, z=1..4 kernels->KhT --------
__global__ __launch_bounds__(256) void ktrans(const float* __restrict__ fcw, const float* __restrict__ kers,
                                              short* __restrict__ WT, short* __restrict__ KhT){
  __shared__ float tile[32][33];
  int z = blockIdx.z;
  const float* src = (z == 0) ? fcw : (kers + (z-1)*65536);
  short* dst = (z == 0) ? WT : (KhT + (z-1)*65536);
  int x0 = blockIdx.x*32, y0 = blockIdx.y*32;
  int tx = threadIdx.x & 31, ty = threadIdx.x >> 5;
  #pragma unroll
  for (int i = 0; i < 32; i += 8) tile[ty+i][tx] = src[(y0+ty+i)*256 + x0+tx];
  __syncthreads();
  #pragma unroll
  for (int i = 0; i < 32; i += 8) dst[(x0+ty+i)*256 + y0+tx] = f2b(tile[tx][ty+i]);
}

// -------- prep: z=0 atom f32->bf16 ; z=1 x f32->bf16 + bitfields + diag. grid (8,128,2) --------
__global__ __launch_bounds__(256) void kprep(const float* __restrict__ atom, const float* __restrict__ x,
                                             short* __restrict__ atom_bf, short* __restrict__ xbf,
                                             unsigned* __restrict__ xbits, float* __restrict__ diag){
  int b = blockIdx.y;
  int row = blockIdx.x*32 + (threadIdx.x >> 3);
  int seg = threadIdx.x & 7;
  if (blockIdx.z == 0){
    const float* p = atom + b*65536 + row*256 + seg*32;
    short* q = atom_bf + b*65536 + row*256 + seg*32;
    #pragma unroll
    for (int k = 0; k < 4; k++){
      f32x4 a = ((const f32x4*)p)[k*2], c = ((const f32x4*)p)[k*2+1];
      bf16x8 o;
      #pragma unroll
      for (int e = 0; e < 4; e++){ o[e] = f2b(a[e]); o[4+e] = f2b(c[e]); }
      ((bf16x8*)q)[k] = o;
    }
  } else {
    const float* p = x + b*65536 + row*256 + seg*32;
    float v[32];
    #pragma unroll
    for (int k = 0; k < 8; k++){
      f32x4 qv = ((const f32x4*)p)[k];
      #pragma unroll
      for (int e = 0; e < 4; e++) v[k*4+e] = qv[e];
    }
    unsigned bits = 0u;
    #pragma unroll
    for (int e = 0; e < 32; e++) if (v[e] > 0.5f) bits |= (1u << e);
    xbits[(b*256 + row)*8 + seg] = bits;
    short* q = xbf + b*65536 + row*256 + seg*32;
    #pragma unroll
    for (int k = 0; k < 4; k++){
      bf16x8 o;
      #pragma unroll
      for (int e = 0; e < 8; e++) o[e] = f2b(v[k*8+e]);
      ((bf16x8*)q)[k] = o;
    }
    if ((row >> 5) == seg) diag[b*256 + row] = v[row & 31];
  }
}

// -------- G2 = atom @ W : G2T[f][m] (scalar) + G2nf[m][f] (vector C^T). grid (4,128) --------
__global__ __launch_bounds__(256) void kG2(const short* __restrict__ WT, const short* __restrict__ atomb,
                                           short* __restrict__ G2T, short* __restrict__ G2nf){
  int b = blockIdx.y;
  int tr = (blockIdx.x >> 1) * 128, tc = (blockIdx.x & 1) * 128;
  int lane = threadIdx.x & 63, wave = threadIdx.x >> 6;
  int wr = (wave >> 1) * 64, wc = (wave & 1) * 64;
  const short* Y = atomb + b * 65536;
  int r0 = tr + wr + (lane & 15);
  int c0 = tc + wc + (lane & 15);
  int koff = (lane >> 4) * 8;
  f32x4 acc[4][4] = {};
  for (int k0 = 0; k0 < 256; k0 += 32){
    bf16x8 af[4], bfr[4];
    #pragma unroll
    for (int i = 0; i < 4; i++) af[i]  = *(const bf16x8*)(WT + (r0 + i*16)*256 + k0 + koff);
    #pragma unroll
    for (int j = 0; j < 4; j++) bfr[j] = *(const bf16x8*)(Y  + (c0 + j*16)*256 + k0 + koff);
    #pragma unroll
    for (int i = 0; i < 4; i++)
      #pragma unroll
      for (int j = 0; j < 4; j++)
        acc[i][j] = __builtin_amdgcn_mfma_f32_16x16x32_bf16(af[i], bfr[j], acc[i][j], 0, 0, 0);
  }
  int fi0 = tr + wr + (lane >> 4) * 4;
  int mj0 = tc + wc + (lane & 15);
  #pragma unroll
  for (int i = 0; i < 4; i++)
    #pragma unroll
    for (int j = 0; j < 4; j++){
      short4v v;
      #pragma unroll
      for (int r = 0; r < 4; r++) v[r] = f2b(acc[i][j][r]);
      *(short4v*)(G2nf + b*65536 + (mj0 + j*16)*256 + fi0 + i*16) = v;   // [m][f]
      #pragma unroll
      for (int r = 0; r < 4; r++)
        G2T[b*65536 + (fi0 + i*16 + r)*256 + mj0 + j*16] = v[r];         // [f][m]
    }
}

// -------- G1 = x @ G2 : P(G2T, xbf), C^T store G1[n][f]. grid (4,128) --------
__global__ __launch_bounds__(256) void kG1(const short* __restrict__ G2T, const short* __restrict__ xbf,
                                           short* __restrict__ G1){
  int b = blockIdx.y;
  int tr = (blockIdx.x >> 1) * 128, tc = (blockIdx.x & 1) * 128;
  int lane = threadIdx.x & 63, wave = threadIdx.x >> 6;
  int wr = (wave >> 1) * 64, wc = (wave & 1) * 64;
  const short* X = G2T + b * 65536;
  const short* Y = xbf + b * 65536;
  int r0 = tr + wr + (lane & 15);
  int c0 = tc + wc + (lane & 15);
  int koff = (lane >> 4) * 8;
  f32x4 acc[4][4] = {};
  for (int k0 = 0; k0 < 256; k0 += 32){
    bf16x8 af[4], bfr[4];
    #pragma unroll
    for (int i = 0; i < 4; i++) af[i]  = *(const bf16x8*)(X + (r0 + i*16)*256 + k0 + koff);
    #pragma unroll
    for (int j = 0; j < 4; j++) bfr[j] = *(const bf16x8*)(Y + (c0 + j*16)*256 + k0 + koff);
    #pragma unroll
    for (int i = 0; i < 4; i++)
      #pragma unroll
      for (int j = 0; j < 4; j++)
        acc[i][j] = __builtin_amdgcn_mfma_f32_16x16x32_bf16(af[i], bfr[j], acc[i][j], 0, 0, 0);
  }
  int fi0 = tr + wr + (lane >> 4) * 4;
  int nj0 = tc + wc + (lane & 15);
  #pragma unroll
  for (int i = 0; i < 4; i++)
    #pragma unroll
    for (int j = 0; j < 4; j++){
      short4v v;
      #pragma unroll
      for (int r = 0; r < 4; r++) v[r] = f2b(acc[i][j][r]);
      *(short4v*)(G1 + b*65536 + (nj0 + j*16)*256 + fi0 + i*16) = v;     // [n][f]
    }
}

// -------- kVec: kvec[sel][h][f] = sum_o K_h[f][o]*w[o] ; kc[sel][h] = sum_o bias*w (+attb). grid (4,2) --------
__global__ __launch_bounds__(256) void kVec(const short* __restrict__ KhT, const float* __restrict__ atts,
                                            const float* __restrict__ attn, const float* __restrict__ biases,
                                            const float* __restrict__ attb,
                                            float* __restrict__ kvecS, float* __restrict__ kvecN,
                                            float* __restrict__ kc){
  __shared__ float red[256];
  int h = blockIdx.x, sel = blockIdx.y;
  int tid = threadIdx.x;
  const float* wv = (sel == 0 ? atts : attn) + h*256;
  const short* K = KhT + h*65536;
  float acc = 0.f;
  for (int o = 0; o < 256; o++) acc += b2f(K[o*256 + tid]) * wv[o];
  (sel == 0 ? kvecS : kvecN)[h*256 + tid] = acc;
  red[tid] = biases[h*256 + tid] * wv[tid];
  __syncthreads();
  for (int s = 128; s > 0; s >>= 1){ if (tid < s) red[tid] += red[tid + s]; __syncthreads(); }
  if (tid == 0) kc[sel*4 + h] = red[0] + (sel == 0 ? attb[h] : 0.f);
}

// -------- kAsn: a_s/a_n[h][b][n] = sum_f h1[n][f]*kvec[f] + kc. grid 512 xcd-swizzled --------
__global__ __launch_bounds__(256) void kAsn(const short* __restrict__ G1, const short* __restrict__ G2nf,
                                            const float* __restrict__ diag, const float* __restrict__ fcb,
                                            const float* __restrict__ epsv,
                                            const float* __restrict__ kvecS, const float* __restrict__ kvecN,
                                            const float* __restrict__ kc,
                                            float* __restrict__ asv_g, float* __restrict__ anv_g){
  __shared__ float fcbL[256], kwsL[256], kwnL[256];
  int wg = blockIdx.x;
  int xcd = wg & 7, idx = wg >> 3;
  int b = xcd + ((idx >> 2) << 3);
  int h = idx & 3;
  int tid = threadIdx.x;
  fcbL[tid] = fcb[tid];
  kwsL[tid] = kvecS[h*256 + tid];
  kwnL[tid] = kvecN[h*256 + tid];
  __syncthreads();
  float epsm1 = epsv[h] - 1.0f;
  float cs = kc[h], cn = kc[4 + h];
  const short* G1b = G1 + b*65536;
  const short* G2b = G2nf + b*65536;
  int seg = tid & 7, nb = tid >> 3;
  for (int t = 0; t < 8; t++){
    int n = t*32 + nb;
    float cj = epsm1 * diag[b*256 + n];
    float ss = 0.f, sn = 0.f;
    #pragma unroll
    for (int q = 0; q < 4; q++){
      bf16x8 g1 = *(const bf16x8*)(G1b + n*256 + seg*32 + q*8);
      bf16x8 g2 = *(const bf16x8*)(G2b + n*256 + seg*32 + q*8);
      #pragma unroll
      for (int e = 0; e < 8; e++){
        int f = seg*32 + q*8 + e;
        float v = b2f(g1[e]) + cj*b2f(g2[e]) + fcbL[f];
        v = v > 0.f ? v : 0.01f*v;
        ss += v * kwsL[f];
        sn += v * kwnL[f];
      }
    }
    ss += __shfl_xor(ss, 1); ss += __shfl_xor(ss, 2); ss += __shfl_xor(ss, 4);
    sn += __shfl_xor(sn, 1); sn += __shfl_xor(sn, 2); sn += __shfl_xor(sn, 4);
    if (seg == 0){
      asv_g[(h*128 + b)*256 + n] = ss + cs;
      anv_g[(h*128 + b)*256 + n] = sn + cn;
    }
  }
}

// ======== kHead: per (h,b,o-half) — feat o-half into LDS, then softmax+PV from LDS ========
// grid 1024 (2 blocks per (h,b)), 512 threads, 76KB LDS -> 2 blocks/CU.
__global__ __launch_bounds__(512, 4) void kHead(const short* __restrict__ KhT, const short* __restrict__ G1,
                                                const short* __restrict__ G2nf, const float* __restrict__ diag,
                                                const float* __restrict__ fcb, const float* __restrict__ epsv,
                                                const float* __restrict__ biases,
                                                const float* __restrict__ asv_g, const float* __restrict__ anv_g,
                                                const unsigned* __restrict__ xbits,
                                                float* __restrict__ out, float* __restrict__ out2){
  __shared__ __align__(16) char featS[65536];     // [128 o-local][256 n] bf16, SWZ
  __shared__ __align__(16) char scratch[10240];   // h1s [128][40] shorts | Pbuf [16][256] bf16 SWZ
  __shared__ float asvL[256], anvL[256];

  short (*h1s)[40] = (short(*)[40])scratch;
  char* Pbuf = scratch;

  int wg = blockIdx.x;              // 0..1023
  int xcd = wg & 7;
  int idx = wg >> 3;                // 0..127
  int b   = xcd + ((idx >> 3) << 3);   // 16 batches per xcd
  int sub = idx & 7;
  int h   = sub >> 1;
  int ob  = sub & 1;
  int o0  = ob * 128;
  int tid = threadIdx.x, lane = tid & 63, w = tid >> 6;

  float epsm1 = epsv[h] - 1.0f;
  const short* KA  = KhT + h*65536;
  const short* G1b = G1  + b*65536;
  const short* G2b = G2nf + b*65536;

  // rebuild assignment: 128 rows x 32 k per sub-stage; thread -> (nl, rkk)
  int nl  = tid >> 2;
  int rkk = (tid & 3) * 8;
  float cjh[2];
  cjh[0] = epsm1 * diag[b*256 + nl];
  cjh[1] = epsm1 * diag[b*256 + 128 + nl];

  // wave geometry (phase 1): 4(o) x 2(n-within-half)
  int ow = w >> 1, nw = w & 1;
  int wro = ow * 32;
  int lr = lane & 15, lq = lane >> 4;
  int koff = lq * 8;

  // ---------------- phase 1: feat[o-half] = h1 @ K_h ----------------
  f32x4 acc[2][2][4] = {};
  for (int k0 = 0; k0 < 256; k0 += 32){
    f32x4 f0 = *(const f32x4*)(fcb + k0 + rkk);
    f32x4 f1 = *(const f32x4*)(fcb + k0 + rkk + 4);
    #pragma unroll
    for (int hh = 0; hh < 2; hh++){
      // rebuild n-half hh into h1s
      {
        bf16x8 g1 = *(const bf16x8*)(G1b + (hh*128 + nl)*256 + k0 + rkk);
        bf16x8 g2 = *(const bf16x8*)(G2b + (hh*128 + nl)*256 + k0 + rkk);
        bf16x8 o;
        #pragma unroll
        for (int e = 0; e < 8; e++){
          float fb = (e < 4) ? f0[e] : f1[e-4];
          float v = b2f(g1[e]) + cjh[hh]*b2f(g2[e]) + fb;
          v = v > 0.f ? v : 0.01f*v;
          o[e] = f2b(v);
        }
        *(bf16x8*)&h1s[nl][rkk] = o;
      }
      __syncthreads();
      bf16x8 hb[4];
      #pragma unroll
      for (int j = 0; j < 4; j++) hb[j] = *(const bf16x8*)&h1s[nw*64 + j*16 + lr][koff];
      #pragma unroll
      for (int i = 0; i < 2; i++){
        bf16x8 af = *(const bf16x8*)(KA + (o0 + wro + i*16 + lr)*256 + k0 + koff);
        #pragma unroll
        for (int j = 0; j < 4; j++)
          acc[i][hh][j] = __builtin_amdgcn_mfma_f32_16x16x32_bf16(af, hb[j], acc[i][hh][j], 0, 0, 0);
      }
      __syncthreads();
    }
  }

  // ---------------- epilogue: bias + featS store (swizzled) ----------------
  int c4 = lq * 4;
  #pragma unroll
  for (int i = 0; i < 2; i++){
    int obase = o0 + wro + i*16 + c4;
    f32x4 bi = *(const f32x4*)(biases + h*256 + obase);
    #pragma unroll
    for (int hh = 0; hh < 2; hh++)
      #pragma unroll
      for (int j = 0; j < 4; j++)
        #pragma unroll
        for (int r = 0; r < 4; r++){
          int ol = wro + i*16 + c4 + r;               // local o
          int nn = hh*128 + nw*64 + j*16 + lr;
          float fv = acc[i][hh][j][r] + bi[r];
          *(short*)(featS + SWZ(ol, nn*2)) = f2b(fv);
        }
  }
  if (tid < 256) asvL[tid] = asv_g[(h*128 + b)*256 + tid];
  else           anvL[tid - 256] = anv_g[(h*128 + b)*256 + tid - 256];
  __syncthreads();

  // ---------------- phase 2: 16 passes of 16 i-rows ----------------
  for (int it0 = 0; it0 < 256; it0 += 16){
    // softmax: 512 threads = 16 rows x 32 segs x 8 cols
    {
      int row = tid >> 5, seg = tid & 31;
      int i = it0 + row;
      float as_i = asvL[i];
      unsigned bits = xbits[(b*256 + i)*8 + (seg >> 2)];
      int sh = (seg & 3) * 8;
      float Lv[8];
      float mx = -3.0e38f;
      #pragma unroll
      for (int e = 0; e < 8; e++){
        float s = as_i + anvL[seg*8 + e];
        float el = s > 0.f ? s : (__expf(s) - 1.0f);
        float L = el + (((bits >> (sh + e)) & 1u) ? 0.f : -1.0e10f);
        Lv[e] = L;
        mx = fmaxf(mx, L);
      }
      mx = fmaxf(mx, __shfl_xor(mx, 1));
      mx = fmaxf(mx, __shfl_xor(mx, 2));
      mx = fmaxf(mx, __shfl_xor(mx, 4));
      mx = fmaxf(mx, __shfl_xor(mx, 8));
      mx = fmaxf(mx, __shfl_xor(mx, 16));
      float sum = 0.f;
      #pragma unroll
      for (int e = 0; e < 8; e++){ float p = __expf(Lv[e] - mx); Lv[e] = p; sum += p; }
      sum += __shfl_xor(sum, 1);
      sum += __shfl_xor(sum, 2);
      sum += __shfl_xor(sum, 4);
      sum += __shfl_xor(sum, 8);
      sum += __shfl_xor(sum, 16);
      float inv = 1.0f / sum;
      bf16x8 pv;
      #pragma unroll
      for (int e = 0; e < 8; e++) pv[e] = f2b(Lv[e] * inv);
      *(bf16x8*)(Pbuf + SWZ(row, seg*16)) = pv;
      if (h == 3 && ob == 0){
        float* o2 = out2 + b*65536 + i*256 + seg*8;
        f32x4 v0, v1;
        #pragma unroll
        for (int e = 0; e < 4; e++){ v0[e] = Lv[e] * inv; v1[e] = Lv[4+e] * inv; }
        *(f32x4*)(o2) = v0;
        *(f32x4*)(o2 + 4) = v1;
      }
    }
    __syncthreads();

    // PV: wave owns 16 o-rows; out^T C-write
    {
      int of = w * 16;
      f32x4 a2 = {};
      for (int k0 = 0; k0 < 256; k0 += 32){
        bf16x8 af = *(const bf16x8*)(featS + SWZ(of + lr, k0*2 + lq*16));
        bf16x8 bf_ = *(const bf16x8*)(Pbuf + SWZ(lr, k0*2 + lq*16));
        a2 = __builtin_amdgcn_mfma_f32_16x16x32_bf16(af, bf_, a2, 0, 0, 0);
      }
      *(f32x4*)(out + (size_t)(b*256 + it0 + lr)*1024 + h*256 + o0 + of + c4) = a2;
    }
    __syncthreads();
  }
}

extern "C" void kernel_launch(void* const* d_in, const int* in_sizes, int n_in,
                              void* d_out, int out_size, void* d_ws, size_t ws_size,
                              hipStream_t stream) {
  const float* atom   = (const float*)d_in[0];
  const float* x      = (const float*)d_in[1];
  const float* fc_w   = (const float*)d_in[2];
  const float* fc_b   = (const float*)d_in[3];
  const float* kers   = (const float*)d_in[4];
  const float* att_s  = (const float*)d_in[5];
  const float* att_n  = (const float*)d_in[6];
  const float* eps    = (const float*)d_in[7];
  const float* biases = (const float*)d_in[8];
  const float* att_b  = (const float*)d_in[9];

  // ws layout (~66.8 MB; ws >= 104 MB established in R3). FIXED R11 overlap:
  // anv_g ends at 2,892,800 -> atomG1 must start at/after that (was 2,883,584: 9216B overlap!)
  char* w = (char*)d_ws;
  short* WT      = (short*)(w);                      // [0,        131072)
  short* KhT     = (short*)(w + 131072);             // [131072,   655360)
  float* diag    = (float*)(w + 655360);             // [655360,   786432)
  unsigned* xbits= (unsigned*)(w + 786432);          // [786432,  1835008)
  float* kvecS   = (float*)(w + 1835008);            // [1835008, 1839104)
  float* kvecN   = (float*)(w + 1839104);            // [1839104, 1843200)
  float* kc      = (float*)(w + 1843200);            // [1843200, 1844224)
  float* asv_g   = (float*)(w + 1844224);            // [1844224, 2368512)
  float* anv_g   = (float*)(w + 2368512);            // [2368512, 2892800)
  short* atomG1  = (short*)(w + 2892800);            // [2892800, 19670016)  atom_bf, then G1
  short* xbf     = (short*)(w + 19670016);           // [19670016, 36447232)
  short* G2T     = (short*)(w + 36447232);           // [36447232, 53224448)
  short* G2nf    = (short*)(w + 53224448);           // [53224448, 70001664)

  float* out  = (float*)d_out;
  float* out2 = out + 33554432;  // B*N*H*D floats

  ktrans<<<dim3(8, 8, 5), 256, 0, stream>>>(fc_w, kers, WT, KhT);
  kprep<<<dim3(8, 128, 2), 256, 0, stream>>>(atom, x, atomG1, xbf, xbits, diag);
  kVec<<<dim3(4, 2), 256, 0, stream>>>(KhT, att_s, att_n, biases, att_b, kvecS, kvecN, kc);
  kG2<<<dim3(4, 128), 256, 0, stream>>>(WT, atomG1, G2T, G2nf);
  kG1<<<dim3(4, 128), 256, 0, stream>>>(G2T, xbf, atomG1);   // G1 overwrites atom_bf (dead)
  kAsn<<<dim3(512), 256, 0, stream>>>(atomG1, G2nf, diag, fc_b, eps, kvecS, kvecN, kc, asv_g, anv_g);
  kHead<<<dim3(1024), 512, 0, stream>>>(KhT, atomG1, G2nf, diag, fc_b, eps, biases,
                                        asv_g, anv_g, xbits, out, out2);
}

// Round 13
// 174.034 us; speedup vs baseline: 1.3234x; 1.3234x over previous
//
#include <hip/hip_runtime.h>

typedef __attribute__((ext_vector_type(8))) short bf16x8;
typedef __attribute__((ext_vector_type(4))) short short4v;
typedef __attribute__((ext_vector_type(4))) float f32x4;

// B=128, N=256, D=256, H=4 ; per-batch matrices are [256][256] (65536 elems)

__device__ __forceinline__ float b2f(short s){
  unsigned u = ((unsigned)(unsigned short)s) << 16;
  return __builtin_bit_cast(float, u);
}
__device__ __forceinline__ short f2b(float f){
  unsigned u = __builtin_bit_cast(unsigned, f);
  u = (u + 0x7FFFu + ((u >> 16) & 1u)) >> 16;
  return (short)(unsigned short)u;
}

// XOR swizzle for 512B-stride rows: spread across the 8 16B-slot orbit.
#define SWZ(row, bytecol) ((((row) * 512) + (bytecol)) ^ (((row) & 7) << 4))

// -------- transpose-convert f32 [256][256] -> bf16 ^T : z=0 fc_w->WT, z=1..4 kernels->KhT --------
__global__ __launch_bounds__(256) void ktrans(const float* __restrict__ fcw, const float* __restrict__ kers,
                                              short* __restrict__ WT, short* __restrict__ KhT){
  __shared__ float tile[32][33];
  int z = blockIdx.z;
  const float* src = (z == 0) ? fcw : (kers + (z-1)*65536);
  short* dst = (z == 0) ? WT : (KhT + (z-1)*65536);
  int x0 = blockIdx.x*32, y0 = blockIdx.y*32;
  int tx = threadIdx.x & 31, ty = threadIdx.x >> 5;
  #pragma unroll
  for (int i = 0; i < 32; i += 8) tile[ty+i][tx] = src[(y0+ty+i)*256 + x0+tx];
  __syncthreads();
  #pragma unroll
  for (int i = 0; i < 32; i += 8) dst[(x0+ty+i)*256 + y0+tx] = f2b(tile[tx][ty+i]);
}

// -------- prep: z=0 atom f32->bf16 ; z=1 x f32->bf16 + bitfields + diag. grid (8,128,2) --------
__global__ __launch_bounds__(256) void kprep(const float* __restrict__ atom, const float* __restrict__ x,
                                             short* __restrict__ atom_bf, short* __restrict__ xbf,
                                             unsigned* __restrict__ xbits, float* __restrict__ diag){
  int b = blockIdx.y;
  int row = blockIdx.x*32 + (threadIdx.x >> 3);
  int seg = threadIdx.x & 7;
  if (blockIdx.z == 0){
    const float* p = atom + b*65536 + row*256 + seg*32;
    short* q = atom_bf + b*65536 + row*256 + seg*32;
    #pragma unroll
    for (int k = 0; k < 4; k++){
      f32x4 a = ((const f32x4*)p)[k*2], c = ((const f32x4*)p)[k*2+1];
      bf16x8 o;
      #pragma unroll
      for (int e = 0; e < 4; e++){ o[e] = f2b(a[e]); o[4+e] = f2b(c[e]); }
      ((bf16x8*)q)[k] = o;
    }
  } else {
    const float* p = x + b*65536 + row*256 + seg*32;
    float v[32];
    #pragma unroll
    for (int k = 0; k < 8; k++){
      f32x4 qv = ((const f32x4*)p)[k];
      #pragma unroll
      for (int e = 0; e < 4; e++) v[k*4+e] = qv[e];
    }
    unsigned bits = 0u;
    #pragma unroll
    for (int e = 0; e < 32; e++) if (v[e] > 0.5f) bits |= (1u << e);
    xbits[(b*256 + row)*8 + seg] = bits;
    short* q = xbf + b*65536 + row*256 + seg*32;
    #pragma unroll
    for (int k = 0; k < 4; k++){
      bf16x8 o;
      #pragma unroll
      for (int e = 0; e < 8; e++) o[e] = f2b(v[k*8+e]);
      ((bf16x8*)q)[k] = o;
    }
    if ((row >> 5) == seg) diag[b*256 + row] = v[row & 31];
  }
}

// -------- G2 = atom @ W : G2T[f][m] (scalar) + G2nf[m][f] (vector C^T). grid (4,128) --------
__global__ __launch_bounds__(256) void kG2(const short* __restrict__ WT, const short* __restrict__ atomb,
                                           short* __restrict__ G2T, short* __restrict__ G2nf){
  int b = blockIdx.y;
  int tr = (blockIdx.x >> 1) * 128, tc = (blockIdx.x & 1) * 128;
  int lane = threadIdx.x & 63, wave = threadIdx.x >> 6;
  int wr = (wave >> 1) * 64, wc = (wave & 1) * 64;
  const short* Y = atomb + b * 65536;
  int r0 = tr + wr + (lane & 15);
  int c0 = tc + wc + (lane & 15);
  int koff = (lane >> 4) * 8;
  f32x4 acc[4][4] = {};
  for (int k0 = 0; k0 < 256; k0 += 32){
    bf16x8 af[4], bfr[4];
    #pragma unroll
    for (int i = 0; i < 4; i++) af[i]  = *(const bf16x8*)(WT + (r0 + i*16)*256 + k0 + koff);
    #pragma unroll
    for (int j = 0; j < 4; j++) bfr[j] = *(const bf16x8*)(Y  + (c0 + j*16)*256 + k0 + koff);
    #pragma unroll
    for (int i = 0; i < 4; i++)
      #pragma unroll
      for (int j = 0; j < 4; j++)
        acc[i][j] = __builtin_amdgcn_mfma_f32_16x16x32_bf16(af[i], bfr[j], acc[i][j], 0, 0, 0);
  }
  int fi0 = tr + wr + (lane >> 4) * 4;
  int mj0 = tc + wc + (lane & 15);
  #pragma unroll
  for (int i = 0; i < 4; i++)
    #pragma unroll
    for (int j = 0; j < 4; j++){
      short4v v;
      #pragma unroll
      for (int r = 0; r < 4; r++) v[r] = f2b(acc[i][j][r]);
      *(short4v*)(G2nf + b*65536 + (mj0 + j*16)*256 + fi0 + i*16) = v;   // [m][f]
      #pragma unroll
      for (int r = 0; r < 4; r++)
        G2T[b*65536 + (fi0 + i*16 + r)*256 + mj0 + j*16] = v[r];         // [f][m]
    }
}

// -------- G1 = x @ G2 : P(G2T, xbf), C^T store G1[n][f]. grid (4,128) --------
__global__ __launch_bounds__(256) void kG1(const short* __restrict__ G2T, const short* __restrict__ xbf,
                                           short* __restrict__ G1){
  int b = blockIdx.y;
  int tr = (blockIdx.x >> 1) * 128, tc = (blockIdx.x & 1) * 128;
  int lane = threadIdx.x & 63, wave = threadIdx.x >> 6;
  int wr = (wave >> 1) * 64, wc = (wave & 1) * 64;
  const short* X = G2T + b * 65536;
  const short* Y = xbf + b * 65536;
  int r0 = tr + wr + (lane & 15);
  int c0 = tc + wc + (lane & 15);
  int koff = (lane >> 4) * 8;
  f32x4 acc[4][4] = {};
  for (int k0 = 0; k0 < 256; k0 += 32){
    bf16x8 af[4], bfr[4];
    #pragma unroll
    for (int i = 0; i < 4; i++) af[i]  = *(const bf16x8*)(X + (r0 + i*16)*256 + k0 + koff);
    #pragma unroll
    for (int j = 0; j < 4; j++) bfr[j] = *(const bf16x8*)(Y + (c0 + j*16)*256 + k0 + koff);
    #pragma unroll
    for (int i = 0; i < 4; i++)
      #pragma unroll
      for (int j = 0; j < 4; j++)
        acc[i][j] = __builtin_amdgcn_mfma_f32_16x16x32_bf16(af[i], bfr[j], acc[i][j], 0, 0, 0);
  }
  int fi0 = tr + wr + (lane >> 4) * 4;
  int nj0 = tc + wc + (lane & 15);
  #pragma unroll
  for (int i = 0; i < 4; i++)
    #pragma unroll
    for (int j = 0; j < 4; j++){
      short4v v;
      #pragma unroll
      for (int r = 0; r < 4; r++) v[r] = f2b(acc[i][j][r]);
      *(short4v*)(G1 + b*65536 + (nj0 + j*16)*256 + fi0 + i*16) = v;     // [n][f]
    }
}

// ======== kHead: per (h,b) — K staged to LDS, feat GEMM (swapped operands) into LDS,
//          then softmax/PV overlapped with double-buffered Pbuf. grid 512, 512 thr. ========
__global__ __launch_bounds__(512, 1) void kHead(const short* __restrict__ KhT, const short* __restrict__ G1,
                                                const short* __restrict__ G2nf, const float* __restrict__ diag,
                                                const float* __restrict__ fcb, const float* __restrict__ epsv,
                                                const float* __restrict__ biases, const float* __restrict__ atts,
                                                const float* __restrict__ attn, const float* __restrict__ attbv,
                                                const unsigned* __restrict__ xbits,
                                                float* __restrict__ out, float* __restrict__ out2){
  __shared__ __align__(16) char featS[131072];    // phase1: K[o][k] SWZ ; then feat^T[o][n] SWZ
  __shared__ __align__(16) char scratch[20480];   // h1s [256][40] | Pb0@0, Pb1@8192, red@16384
  __shared__ float asvL[256], anvL[256], fcbL[256];

  short (*h1s)[40] = (short(*)[40])scratch;
  char* Pb0 = scratch;
  char* Pb1 = scratch + 8192;
  float (*red_s)[64] = (float(*)[64])(scratch + 16384);
  float (*red_n)[64] = (float(*)[64])(scratch + 16384 + 2048);

  int wg = blockIdx.x;
  int xcd = wg & 7, idx = wg >> 3;
  int b = xcd + ((idx >> 2) << 3);   // 16 batches per xcd, 4 heads adjacent
  int h = idx & 3;
  int tid = threadIdx.x, lane = tid & 63, w = tid >> 6;
  float epsm1 = epsv[h] - 1.0f;
  const short* KA  = KhT + h*65536;
  const short* G1b = G1  + b*65536;
  const short* G2b = G2nf + b*65536;

  // ---- stage K (128 KB) into featS, SWZ[o][k]; stage fcb ----
  {
    int o = tid >> 1, half = (tid & 1) * 128;
    #pragma unroll
    for (int q = 0; q < 16; q++){
      int kk = half + q*8;
      bf16x8 v = *(const bf16x8*)(KA + o*256 + kk);
      *(bf16x8*)(featS + SWZ(o, kk*2)) = v;
    }
    if (tid < 256) fcbL[tid] = fcb[tid];
  }

  // rebuild assignment: thread -> (row nl 0..255, 16-k half)
  int nl = tid >> 1, rkk = (tid & 1) * 16;
  float cj = epsm1 * diag[b*256 + nl];

  // wave geometry (phase 1): X = h1 (n-rows), Y = K (o-rows)
  int wro = (w >> 2) * 128;   // o-half
  int wn  = (w & 3) * 64;     // n-quarter
  int lr = lane & 15, lq = lane >> 4;
  int koff = lq * 8;

  // prefetch G1/G2 for k-step 0
  bf16x8 p1a = *(const bf16x8*)(G1b + nl*256 + rkk);
  bf16x8 p1b = *(const bf16x8*)(G1b + nl*256 + rkk + 8);
  bf16x8 p2a = *(const bf16x8*)(G2b + nl*256 + rkk);
  bf16x8 p2b = *(const bf16x8*)(G2b + nl*256 + rkk + 8);

  // ---------------- phase 1: feat = h1 @ K_h (acc[j_n][i_o]) ----------------
  f32x4 acc[4][8] = {};
  for (int t = 0; t < 8; t++){
    int k0 = t*32;
    // build h1 tile (k0..k0+31) from prefetched regs
    {
      bf16x8 o1, o2;
      #pragma unroll
      for (int e = 0; e < 8; e++){
        float v = b2f(p1a[e]) + cj*b2f(p2a[e]) + fcbL[k0 + rkk + e];
        v = v > 0.f ? v : 0.01f*v;
        o1[e] = f2b(v);
      }
      #pragma unroll
      for (int e = 0; e < 8; e++){
        float v = b2f(p1b[e]) + cj*b2f(p2b[e]) + fcbL[k0 + rkk + 8 + e];
        v = v > 0.f ? v : 0.01f*v;
        o2[e] = f2b(v);
      }
      *(bf16x8*)&h1s[nl][rkk] = o1;
      *(bf16x8*)&h1s[nl][rkk + 8] = o2;
    }
    __syncthreads();
    if (t < 7){
      int kn = k0 + 32;
      p1a = *(const bf16x8*)(G1b + nl*256 + kn + rkk);
      p1b = *(const bf16x8*)(G1b + nl*256 + kn + rkk + 8);
      p2a = *(const bf16x8*)(G2b + nl*256 + kn + rkk);
      p2b = *(const bf16x8*)(G2b + nl*256 + kn + rkk + 8);
    }
    bf16x8 af[4];
    #pragma unroll
    for (int j = 0; j < 4; j++) af[j] = *(const bf16x8*)&h1s[wn + j*16 + lr][koff];
    #pragma unroll
    for (int i = 0; i < 8; i++){
      bf16x8 bfv = *(const bf16x8*)(featS + SWZ(wro + i*16 + lr, (k0 + koff)*2));
      #pragma unroll
      for (int j = 0; j < 4; j++)
        acc[j][i] = __builtin_amdgcn_mfma_f32_16x16x32_bf16(af[j], bfv, acc[j][i], 0, 0, 0);
    }
    __syncthreads();
  }

  // ---------------- epilogue: bias + vectorized feat^T stores + a_s/a_n partials ----------------
  float ps[4][4] = {}, pn[4][4] = {};
  #pragma unroll
  for (int i = 0; i < 8; i++){
    int od = wro + i*16 + lr;                       // o (lane-dim)
    float bi  = biases[h*256 + od];
    float wsv = atts[h*256 + od];
    float wnv = attn[h*256 + od];
    #pragma unroll
    for (int j = 0; j < 4; j++){
      short4v sv;
      #pragma unroll
      for (int r = 0; r < 4; r++){
        float fv = acc[j][i][r] + bi;
        sv[r] = f2b(fv);
        ps[j][r] += fv * wsv;
        pn[j][r] += fv * wnv;
      }
      *(short4v*)(featS + SWZ(od, (wn + j*16 + lq*4)*2) ) = sv;   // 8B store
    }
  }
  #pragma unroll
  for (int j = 0; j < 4; j++)
    #pragma unroll
    for (int r = 0; r < 4; r++){
      float s = ps[j][r], nv = pn[j][r];
      s += __shfl_xor(s, 1); s += __shfl_xor(s, 2); s += __shfl_xor(s, 4); s += __shfl_xor(s, 8);
      nv += __shfl_xor(nv, 1); nv += __shfl_xor(nv, 2); nv += __shfl_xor(nv, 4); nv += __shfl_xor(nv, 8);
      ps[j][r] = s; pn[j][r] = nv;
    }
  __syncthreads();            // h1s dead; red overlay safe
  if (lr == 0){
    #pragma unroll
    for (int j = 0; j < 4; j++)
      #pragma unroll
      for (int r = 0; r < 4; r++){
        red_s[w][j*16 + lq*4 + r] = ps[j][r];
        red_n[w][j*16 + lq*4 + r] = pn[j][r];
      }
  }
  __syncthreads();
  if (tid < 256){
    int q = tid >> 6, nn = tid & 63;
    asvL[tid] = red_s[q][nn] + red_s[q+4][nn] + attbv[h];
    anvL[tid] = red_n[q][nn] + red_n[q+4][nn];
  }
  __syncthreads();

  // ---------------- phase 2: 16 passes, PV(t) overlapped with softmax(t+1) ----------------
  int row = tid >> 5, seg = tid & 31;
  // softmax pass 0 -> Pb0
  #pragma unroll 1
  for (int pre = 0; pre < 1; pre++){
    int i = row;
    float as_i = asvL[i];
    unsigned bits = xbits[(b*256 + i)*8 + (seg >> 2)];
    int sh = (seg & 3) * 8;
    float Lv[8]; float mx = -3.0e38f;
    #pragma unroll
    for (int e = 0; e < 8; e++){
      float s = as_i + anvL[seg*8 + e];
      float el = s > 0.f ? s : (__expf(s) - 1.0f);
      float L = el + (((bits >> (sh + e)) & 1u) ? 0.f : -1.0e10f);
      Lv[e] = L; mx = fmaxf(mx, L);
    }
    mx = fmaxf(mx, __shfl_xor(mx, 1)); mx = fmaxf(mx, __shfl_xor(mx, 2));
    mx = fmaxf(mx, __shfl_xor(mx, 4)); mx = fmaxf(mx, __shfl_xor(mx, 8));
    mx = fmaxf(mx, __shfl_xor(mx, 16));
    float sum = 0.f;
    #pragma unroll
    for (int e = 0; e < 8; e++){ float p = __expf(Lv[e] - mx); Lv[e] = p; sum += p; }
    sum += __shfl_xor(sum, 1); sum += __shfl_xor(sum, 2); sum += __shfl_xor(sum, 4);
    sum += __shfl_xor(sum, 8); sum += __shfl_xor(sum, 16);
    float inv = 1.0f / sum;
    bf16x8 pv;
    #pragma unroll
    for (int e = 0; e < 8; e++) pv[e] = f2b(Lv[e] * inv);
    *(bf16x8*)(Pb0 + SWZ(row, seg*16)) = pv;
    if (h == 3){
      float* o2 = out2 + b*65536 + i*256 + seg*8;
      f32x4 v0, v1;
      #pragma unroll
      for (int e = 0; e < 4; e++){ v0[e] = Lv[e]*inv; v1[e] = Lv[4+e]*inv; }
      *(f32x4*)(o2) = v0; *(f32x4*)(o2 + 4) = v1;
    }
  }

  int o0w = w * 32;
  for (int t = 0; t < 16; t++){
    __syncthreads();
    int it0 = t * 16;
    char* Pr = (t & 1) ? Pb1 : Pb0;
    // PV: A = feat^T o-rows (reg-dim o), B = P i-rows (lane-dim i)
    f32x4 a2[2] = {};
    for (int k0 = 0; k0 < 256; k0 += 32){
      bf16x8 bfp = *(const bf16x8*)(Pr + SWZ(lr, (k0 + koff)*2));
      #pragma unroll
      for (int ii = 0; ii < 2; ii++){
        bf16x8 afv = *(const bf16x8*)(featS + SWZ(o0w + ii*16 + lr, (k0 + koff)*2));
        a2[ii] = __builtin_amdgcn_mfma_f32_16x16x32_bf16(afv, bfp, a2[ii], 0, 0, 0);
      }
    }
    #pragma unroll
    for (int ii = 0; ii < 2; ii++)
      *(f32x4*)(out + (size_t)(b*256 + it0 + lr)*1024 + h*256 + o0w + ii*16 + lq*4) = a2[ii];

    if (t < 15){
      char* Pw = (t & 1) ? Pb0 : Pb1;
      int i = it0 + 16 + row;
      float as_i = asvL[i];
      unsigned bits = xbits[(b*256 + i)*8 + (seg >> 2)];
      int sh = (seg & 3) * 8;
      float Lv[8]; float mx = -3.0e38f;
      #pragma unroll
      for (int e = 0; e < 8; e++){
        float s = as_i + anvL[seg*8 + e];
        float el = s > 0.f ? s : (__expf(s) - 1.0f);
        float L = el + (((bits >> (sh + e)) & 1u) ? 0.f : -1.0e10f);
        Lv[e] = L; mx = fmaxf(mx, L);
      }
      mx = fmaxf(mx, __shfl_xor(mx, 1)); mx = fmaxf(mx, __shfl_xor(mx, 2));
      mx = fmaxf(mx, __shfl_xor(mx, 4)); mx = fmaxf(mx, __shfl_xor(mx, 8));
      mx = fmaxf(mx, __shfl_xor(mx, 16));
      float sum = 0.f;
      #pragma unroll
      for (int e = 0; e < 8; e++){ float p = __expf(Lv[e] - mx); Lv[e] = p; sum += p; }
      sum += __shfl_xor(sum, 1); sum += __shfl_xor(sum, 2); sum += __shfl_xor(sum, 4);
      sum += __shfl_xor(sum, 8); sum += __shfl_xor(sum, 16);
      float inv = 1.0f / sum;
      bf16x8 pv;
      #pragma unroll
      for (int e = 0; e < 8; e++) pv[e] = f2b(Lv[e] * inv);
      *(bf16x8*)(Pw + SWZ(row, seg*16)) = pv;
      if (h == 3){
        float* o2 = out2 + b*65536 + i*256 + seg*8;
        f32x4 v0, v1;
        #pragma unroll
        for (int e = 0; e < 4; e++){ v0[e] = Lv[e]*inv; v1[e] = Lv[4+e]*inv; }
        *(f32x4*)(o2) = v0; *(f32x4*)(o2 + 4) = v1;
      }
    }
  }
}

extern "C" void kernel_launch(void* const* d_in, const int* in_sizes, int n_in,
                              void* d_out, int out_size, void* d_ws, size_t ws_size,
                              hipStream_t stream) {
  const float* atom   = (const float*)d_in[0];
  const float* x      = (const float*)d_in[1];
  const float* fc_w   = (const float*)d_in[2];
  const float* fc_b   = (const float*)d_in[3];
  const float* kers   = (const float*)d_in[4];
  const float* att_s  = (const float*)d_in[5];
  const float* att_n  = (const float*)d_in[6];
  const float* eps    = (const float*)d_in[7];
  const float* biases = (const float*)d_in[8];
  const float* att_b  = (const float*)d_in[9];

  // ws layout (~67 MB)
  char* w = (char*)d_ws;
  short* WT      = (short*)(w);                      // 128 KB
  short* KhT     = (short*)(w + 131072);             // 512 KB
  float* diag    = (float*)(w + 655360);             // 128 KB
  unsigned* xbits= (unsigned*)(w + 786432);          // 1 MB
  short* atomG1  = (short*)(w + 1835008);            // 16 MB: atom_bf, then G1
  short* xbf     = (short*)(w + 18612224);           // 16 MB
  short* G2T     = (short*)(w + 35389440);           // 16 MB
  short* G2nf    = (short*)(w + 52166656);           // 16 MB

  float* out  = (float*)d_out;
  float* out2 = out + 33554432;  // B*N*H*D floats

  ktrans<<<dim3(8, 8, 5), 256, 0, stream>>>(fc_w, kers, WT, KhT);
  kprep<<<dim3(8, 128, 2), 256, 0, stream>>>(atom, x, atomG1, xbf, xbits, diag);
  kG2<<<dim3(4, 128), 256, 0, stream>>>(WT, atomG1, G2T, G2nf);
  kG1<<<dim3(4, 128), 256, 0, stream>>>(G2T, xbf, atomG1);   // G1 overwrites atom_bf (dead)

  kHead<<<dim3(512), 512, 0, stream>>>(KhT, atomG1, G2nf, diag, fc_b, eps,
                                       biases, att_s, att_n, att_b, xbits, out, out2);
}

// Round 14
// 171.191 us; speedup vs baseline: 1.3454x; 1.0166x over previous
//
#include <hip/hip_runtime.h>

typedef __attribute__((ext_vector_type(8))) short bf16x8;
typedef __attribute__((ext_vector_type(4))) short short4v;
typedef __attribute__((ext_vector_type(4))) float f32x4;

// B=128, N=256, D=256, H=4 ; per-batch matrices are [256][256] (65536 elems)

__device__ __forceinline__ float b2f(short s){
  unsigned u = ((unsigned)(unsigned short)s) << 16;
  return __builtin_bit_cast(float, u);
}
__device__ __forceinline__ short f2b(float f){
  unsigned u = __builtin_bit_cast(unsigned, f);
  u = (u + 0x7FFFu + ((u >> 16) & 1u)) >> 16;
  return (short)(unsigned short)u;
}

// XOR swizzle for 512B-stride rows: spread across the 8 16B-slot orbit.
#define SWZ(row, bytecol) ((((row) * 512) + (bytecol)) ^ (((row) & 7) << 4))

// -------- transpose-convert f32 [256][256] -> bf16 ^T : z=0 fc_w->WT, z=1..4 kernels->KhT --------
__global__ __launch_bounds__(256) void ktrans(const float* __restrict__ fcw, const float* __restrict__ kers,
                                              short* __restrict__ WT, short* __restrict__ KhT){
  __shared__ float tile[32][33];
  int z = blockIdx.z;
  const float* src = (z == 0) ? fcw : (kers + (z-1)*65536);
  short* dst = (z == 0) ? WT : (KhT + (z-1)*65536);
  int x0 = blockIdx.x*32, y0 = blockIdx.y*32;
  int tx = threadIdx.x & 31, ty = threadIdx.x >> 5;
  #pragma unroll
  for (int i = 0; i < 32; i += 8) tile[ty+i][tx] = src[(y0+ty+i)*256 + x0+tx];
  __syncthreads();
  #pragma unroll
  for (int i = 0; i < 32; i += 8) dst[(x0+ty+i)*256 + y0+tx] = f2b(tile[tx][ty+i]);
}

// -------- prep: z=0 atom f32->bf16 ; z=1 x f32->bf16 + bitfields + diag. grid (8,128,2) --------
__global__ __launch_bounds__(256) void kprep(const float* __restrict__ atom, const float* __restrict__ x,
                                             short* __restrict__ atom_bf, short* __restrict__ xbf,
                                             unsigned* __restrict__ xbits, float* __restrict__ diag){
  int b = blockIdx.y;
  int row = blockIdx.x*32 + (threadIdx.x >> 3);
  int seg = threadIdx.x & 7;
  if (blockIdx.z == 0){
    const float* p = atom + b*65536 + row*256 + seg*32;
    short* q = atom_bf + b*65536 + row*256 + seg*32;
    #pragma unroll
    for (int k = 0; k < 4; k++){
      f32x4 a = ((const f32x4*)p)[k*2], c = ((const f32x4*)p)[k*2+1];
      bf16x8 o;
      #pragma unroll
      for (int e = 0; e < 4; e++){ o[e] = f2b(a[e]); o[4+e] = f2b(c[e]); }
      ((bf16x8*)q)[k] = o;
    }
  } else {
    const float* p = x + b*65536 + row*256 + seg*32;
    float v[32];
    #pragma unroll
    for (int k = 0; k < 8; k++){
      f32x4 qv = ((const f32x4*)p)[k];
      #pragma unroll
      for (int e = 0; e < 4; e++) v[k*4+e] = qv[e];
    }
    unsigned bits = 0u;
    #pragma unroll
    for (int e = 0; e < 32; e++) if (v[e] > 0.5f) bits |= (1u << e);
    xbits[(b*256 + row)*8 + seg] = bits;
    short* q = xbf + b*65536 + row*256 + seg*32;
    #pragma unroll
    for (int k = 0; k < 4; k++){
      bf16x8 o;
      #pragma unroll
      for (int e = 0; e < 8; e++) o[e] = f2b(v[k*8+e]);
      ((bf16x8*)q)[k] = o;
    }
    if ((row >> 5) == seg) diag[b*256 + row] = v[row & 31];
  }
}

// ======== kG12: per (b, f-half) — G2-half = atom@W into LDS (G2T layout) + G2nf global,
//          then G1-half = x@G2 from LDS. grid 256, 512 thr, one barrier. ========
__global__ __launch_bounds__(512, 1) void kG12(const short* __restrict__ WT, const short* __restrict__ atomb,
                                               const short* __restrict__ xbf,
                                               short* __restrict__ G2nf, short* __restrict__ G1){
  __shared__ __align__(16) char G2s[65536];   // [128 f-local][256 m] bf16, SWZ
  int wg = blockIdx.x;                 // 0..255
  int xcd = wg & 7, idx = wg >> 3;     // idx 0..31
  int b  = xcd + ((idx >> 1) << 3);    // 16 batches per xcd
  int fh = idx & 1;
  int tid = threadIdx.x, lane = tid & 63, w = tid >> 6;
  int lr = lane & 15, lq = lane >> 4, koff = lq * 8;

  // ---- GEMM1: D[m][f-local] = atom @ W-half ; waves 4m x 2f ----
  {
    int wm = (w >> 1) * 64, wf = (w & 1) * 64;
    const short* Ab = atomb + b*65536;
    const short* Bw = WT + (fh*128 + wf)*256;
    f32x4 acc[4][4] = {};
    for (int k0 = 0; k0 < 256; k0 += 32){
      bf16x8 af[4], bfr[4];
      #pragma unroll
      for (int i = 0; i < 4; i++) af[i]  = *(const bf16x8*)(Ab + (wm + i*16 + lr)*256 + k0 + koff);
      #pragma unroll
      for (int j = 0; j < 4; j++) bfr[j] = *(const bf16x8*)(Bw + (j*16 + lr)*256 + k0 + koff);
      #pragma unroll
      for (int i = 0; i < 4; i++)
        #pragma unroll
        for (int j = 0; j < 4; j++)
          acc[i][j] = __builtin_amdgcn_mfma_f32_16x16x32_bf16(af[i], bfr[j], acc[i][j], 0, 0, 0);
    }
    // m = wm + i*16 + lq*4 + r (reg-dim), f_local = wf + j*16 + lr (lane-dim)
    #pragma unroll
    for (int i = 0; i < 4; i++)
      #pragma unroll
      for (int j = 0; j < 4; j++){
        short4v v;
        #pragma unroll
        for (int r = 0; r < 4; r++) v[r] = f2b(acc[i][j][r]);
        int fl = wf + j*16 + lr;
        int m0 = wm + i*16 + lq*4;
        *(short4v*)(G2s + SWZ(fl, m0*2)) = v;                          // LDS G2T[f][m] 8B
        #pragma unroll
        for (int r = 0; r < 4; r++)
          G2nf[b*65536 + (m0 + r)*256 + fh*128 + fl] = v[r];           // global [m][f]
      }
  }
  __syncthreads();

  // ---- GEMM2: D[f-local][n] = G2T-LDS @ x ; waves 2f x 4n ----
  {
    int wf2 = (w >> 2) * 64, wn2 = (w & 3) * 64;
    const short* Xb = xbf + b*65536;
    f32x4 acc[4][4] = {};
    for (int k0 = 0; k0 < 256; k0 += 32){
      bf16x8 af[4], bfr[4];
      #pragma unroll
      for (int i = 0; i < 4; i++) af[i]  = *(const bf16x8*)(G2s + SWZ(wf2 + i*16 + lr, (k0 + koff)*2));
      #pragma unroll
      for (int j = 0; j < 4; j++) bfr[j] = *(const bf16x8*)(Xb + (wn2 + j*16 + lr)*256 + k0 + koff);
      #pragma unroll
      for (int i = 0; i < 4; i++)
        #pragma unroll
        for (int j = 0; j < 4; j++)
          acc[i][j] = __builtin_amdgcn_mfma_f32_16x16x32_bf16(af[i], bfr[j], acc[i][j], 0, 0, 0);
    }
    // C^T: n = wn2 + j*16 + lr (lane), f = fh*128 + wf2 + i*16 + lq*4 + r (reg)
    #pragma unroll
    for (int i = 0; i < 4; i++)
      #pragma unroll
      for (int j = 0; j < 4; j++){
        short4v v;
        #pragma unroll
        for (int r = 0; r < 4; r++) v[r] = f2b(acc[i][j][r]);
        *(short4v*)(G1 + b*65536 + (wn2 + j*16 + lr)*256 + fh*128 + wf2 + i*16 + lq*4) = v;
      }
  }
}

// ======== kHead: per (h,b) — K in LDS (read-only), barrier-free phase 1 with
//          wave-private h1 rebuild; epilogue -> featS; overlapped softmax/PV. ========
__global__ __launch_bounds__(512, 1) void kHead(const short* __restrict__ KhT, const short* __restrict__ G1,
                                                const short* __restrict__ G2nf, const float* __restrict__ diag,
                                                const float* __restrict__ fcb, const float* __restrict__ epsv,
                                                const float* __restrict__ biases, const float* __restrict__ atts,
                                                const float* __restrict__ attn, const float* __restrict__ attbv,
                                                const unsigned* __restrict__ xbits,
                                                float* __restrict__ out, float* __restrict__ out2){
  __shared__ __align__(16) char featS[131072];    // phase1: K[o][k] SWZ ; then feat^T[o][n] SWZ
  __shared__ __align__(16) char scratch[24576];   // Pb0@0, Pb1@8192 ; red@16384 then xbitsL@16384
  __shared__ float asvL[256], anvL[256], fcbL[256];

  char* Pb0 = scratch;
  char* Pb1 = scratch + 8192;
  float (*red_s)[64] = (float(*)[64])(scratch + 16384);
  float (*red_n)[64] = (float(*)[64])(scratch + 16384 + 2048);
  unsigned* xbitsL = (unsigned*)(scratch + 16384);

  int wg = blockIdx.x;
  int xcd = wg & 7, idx = wg >> 3;
  int b = xcd + ((idx >> 2) << 3);   // 16 batches per xcd, 4 heads adjacent
  int h = idx & 3;
  int tid = threadIdx.x, lane = tid & 63, w = tid >> 6;
  float epsm1 = epsv[h] - 1.0f;
  const short* KA  = KhT + h*65536;
  const short* G1b = G1  + b*65536;
  const short* G2b = G2nf + b*65536;

  // ---- stage K (128 KB) into featS, SWZ[o][k]; stage fcb ----
  {
    int o = tid >> 1, half = (tid & 1) * 128;
    #pragma unroll
    for (int q = 0; q < 16; q++){
      int kk = half + q*8;
      bf16x8 v = *(const bf16x8*)(KA + o*256 + kk);
      *(bf16x8*)(featS + SWZ(o, kk*2)) = v;
    }
    if (tid < 256) fcbL[tid] = fcb[tid];
  }

  // wave geometry (phase 1): waves (w>>2)=o-half, (w&3)=n-quarter
  int wro = (w >> 2) * 128;
  int wn  = (w & 3) * 64;
  int lr = lane & 15, lq = lane >> 4;
  int koff = lq * 8;
  float cj[4];
  #pragma unroll
  for (int j = 0; j < 4; j++) cj[j] = epsm1 * diag[b*256 + wn + j*16 + lr];

  __syncthreads();   // K + fcb staged

  // ---------------- phase 1: feat = h1 @ K_h — NO barriers (K read-only) ----------------
  f32x4 acc[4][8] = {};
  for (int t = 0; t < 8; t++){
    int k0 = t*32;
    f32x4 fb0 = *(const f32x4*)&fcbL[k0 + koff];
    f32x4 fb1 = *(const f32x4*)&fcbL[k0 + koff + 4];
    bf16x8 af[4];
    #pragma unroll
    for (int j = 0; j < 4; j++){
      int row = wn + j*16 + lr;
      bf16x8 g1 = *(const bf16x8*)(G1b + row*256 + k0 + koff);
      bf16x8 g2 = *(const bf16x8*)(G2b + row*256 + k0 + koff);
      bf16x8 o;
      #pragma unroll
      for (int e = 0; e < 8; e++){
        float fbv = (e < 4) ? fb0[e] : fb1[e-4];
        float v = b2f(g1[e]) + cj[j]*b2f(g2[e]) + fbv;
        v = v > 0.f ? v : 0.01f*v;
        o[e] = f2b(v);
      }
      af[j] = o;
    }
    #pragma unroll
    for (int i = 0; i < 8; i++){
      bf16x8 bfv = *(const bf16x8*)(featS + SWZ(wro + i*16 + lr, (k0 + koff)*2));
      #pragma unroll
      for (int j = 0; j < 4; j++)
        acc[j][i] = __builtin_amdgcn_mfma_f32_16x16x32_bf16(af[j], bfv, acc[j][i], 0, 0, 0);
    }
  }
  __syncthreads();   // all K reads done; featS reusable

  // ---------------- epilogue: bias + vectorized feat^T stores + a_s/a_n partials ----------------
  float ps[4][4] = {}, pn[4][4] = {};
  #pragma unroll
  for (int i = 0; i < 8; i++){
    int od = wro + i*16 + lr;                       // o (lane-dim)
    float bi  = biases[h*256 + od];
    float wsv = atts[h*256 + od];
    float wnv = attn[h*256 + od];
    #pragma unroll
    for (int j = 0; j < 4; j++){
      short4v sv;
      #pragma unroll
      for (int r = 0; r < 4; r++){
        float fv = acc[j][i][r] + bi;
        sv[r] = f2b(fv);
        ps[j][r] += fv * wsv;
        pn[j][r] += fv * wnv;
      }
      *(short4v*)(featS + SWZ(od, (wn + j*16 + lq*4)*2) ) = sv;   // 8B store
    }
  }
  #pragma unroll
  for (int j = 0; j < 4; j++)
    #pragma unroll
    for (int r = 0; r < 4; r++){
      float s = ps[j][r], nv = pn[j][r];
      s += __shfl_xor(s, 1); s += __shfl_xor(s, 2); s += __shfl_xor(s, 4); s += __shfl_xor(s, 8);
      nv += __shfl_xor(nv, 1); nv += __shfl_xor(nv, 2); nv += __shfl_xor(nv, 4); nv += __shfl_xor(nv, 8);
      ps[j][r] = s; pn[j][r] = nv;
    }
  if (lr == 0){
    #pragma unroll
    for (int j = 0; j < 4; j++)
      #pragma unroll
      for (int r = 0; r < 4; r++){
        red_s[w][j*16 + lq*4 + r] = ps[j][r];
        red_n[w][j*16 + lq*4 + r] = pn[j][r];
      }
  }
  __syncthreads();
  if (tid < 256){
    int q = tid >> 6, nn = tid & 63;
    asvL[tid] = red_s[q][nn] + red_s[q+4][nn] + attbv[h];
    anvL[tid] = red_n[q][nn] + red_n[q+4][nn];
  }
  __syncthreads();   // red consumed -> xbitsL overlay safe
  {
    const unsigned* xb = xbits + b*2048;
    #pragma unroll
    for (int q = 0; q < 4; q++) xbitsL[tid*4 + q] = xb[tid*4 + q];
  }
  __syncthreads();

  // ---------------- phase 2: 16 passes, PV(t) overlapped with softmax(t+1) ----------------
  int row = tid >> 5, seg = tid & 31;
  {
    int i = row;
    float as_i = asvL[i];
    unsigned bits = xbitsL[i*8 + (seg >> 2)];
    int sh = (seg & 3) * 8;
    float Lv[8]; float mx = -3.0e38f;
    #pragma unroll
    for (int e = 0; e < 8; e++){
      float s = as_i + anvL[seg*8 + e];
      float el = s > 0.f ? s : (__expf(s) - 1.0f);
      float L = el + (((bits >> (sh + e)) & 1u) ? 0.f : -1.0e10f);
      Lv[e] = L; mx = fmaxf(mx, L);
    }
    mx = fmaxf(mx, __shfl_xor(mx, 1)); mx = fmaxf(mx, __shfl_xor(mx, 2));
    mx = fmaxf(mx, __shfl_xor(mx, 4)); mx = fmaxf(mx, __shfl_xor(mx, 8));
    mx = fmaxf(mx, __shfl_xor(mx, 16));
    float sum = 0.f;
    #pragma unroll
    for (int e = 0; e < 8; e++){ float p = __expf(Lv[e] - mx); Lv[e] = p; sum += p; }
    sum += __shfl_xor(sum, 1); sum += __shfl_xor(sum, 2); sum += __shfl_xor(sum, 4);
    sum += __shfl_xor(sum, 8); sum += __shfl_xor(sum, 16);
    float inv = 1.0f / sum;
    bf16x8 pv;
    #pragma unroll
    for (int e = 0; e < 8; e++) pv[e] = f2b(Lv[e] * inv);
    *(bf16x8*)(Pb0 + SWZ(row, seg*16)) = pv;
    if (h == 3){
      float* o2 = out2 + b*65536 + i*256 + seg*8;
      f32x4 v0, v1;
      #pragma unroll
      for (int e = 0; e < 4; e++){ v0[e] = Lv[e]*inv; v1[e] = Lv[4+e]*inv; }
      *(f32x4*)(o2) = v0; *(f32x4*)(o2 + 4) = v1;
    }
  }

  int o0w = w * 32;
  for (int t = 0; t < 16; t++){
    __syncthreads();
    int it0 = t * 16;
    char* Pr = (t & 1) ? Pb1 : Pb0;
    f32x4 a2[2] = {};
    for (int k0 = 0; k0 < 256; k0 += 32){
      bf16x8 bfp = *(const bf16x8*)(Pr + SWZ(lr, (k0 + koff)*2));
      #pragma unroll
      for (int ii = 0; ii < 2; ii++){
        bf16x8 afv = *(const bf16x8*)(featS + SWZ(o0w + ii*16 + lr, (k0 + koff)*2));
        a2[ii] = __builtin_amdgcn_mfma_f32_16x16x32_bf16(afv, bfp, a2[ii], 0, 0, 0);
      }
    }
    #pragma unroll
    for (int ii = 0; ii < 2; ii++)
      *(f32x4*)(out + (size_t)(b*256 + it0 + lr)*1024 + h*256 + o0w + ii*16 + lq*4) = a2[ii];

    if (t < 15){
      char* Pw = (t & 1) ? Pb0 : Pb1;
      int i = it0 + 16 + row;
      float as_i = asvL[i];
      unsigned bits = xbitsL[i*8 + (seg >> 2)];
      int sh = (seg & 3) * 8;
      float Lv[8]; float mx = -3.0e38f;
      #pragma unroll
      for (int e = 0; e < 8; e++){
        float s = as_i + anvL[seg*8 + e];
        float el = s > 0.f ? s : (__expf(s) - 1.0f);
        float L = el + (((bits >> (sh + e)) & 1u) ? 0.f : -1.0e10f);
        Lv[e] = L; mx = fmaxf(mx, L);
      }
      mx = fmaxf(mx, __shfl_xor(mx, 1)); mx = fmaxf(mx, __shfl_xor(mx, 2));
      mx = fmaxf(mx, __shfl_xor(mx, 4)); mx = fmaxf(mx, __shfl_xor(mx, 8));
      mx = fmaxf(mx, __shfl_xor(mx, 16));
      float sum = 0.f;
      #pragma unroll
      for (int e = 0; e < 8; e++){ float p = __expf(Lv[e] - mx); Lv[e] = p; sum += p; }
      sum += __shfl_xor(sum, 1); sum += __shfl_xor(sum, 2); sum += __shfl_xor(sum, 4);
      sum += __shfl_xor(sum, 8); sum += __shfl_xor(sum, 16);
      float inv = 1.0f / sum;
      bf16x8 pv;
      #pragma unroll
      for (int e = 0; e < 8; e++) pv[e] = f2b(Lv[e] * inv);
      *(bf16x8*)(Pw + SWZ(row, seg*16)) = pv;
      if (h == 3){
        float* o2 = out2 + b*65536 + i*256 + seg*8;
        f32x4 v0, v1;
        #pragma unroll
        for (int e = 0; e < 4; e++){ v0[e] = Lv[e]*inv; v1[e] = Lv[4+e]*inv; }
        *(f32x4*)(o2) = v0; *(f32x4*)(o2 + 4) = v1;
      }
    }
  }
}

extern "C" void kernel_launch(void* const* d_in, const int* in_sizes, int n_in,
                              void* d_out, int out_size, void* d_ws, size_t ws_size,
                              hipStream_t stream) {
  const float* atom   = (const float*)d_in[0];
  const float* x      = (const float*)d_in[1];
  const float* fc_w   = (const float*)d_in[2];
  const float* fc_b   = (const float*)d_in[3];
  const float* kers   = (const float*)d_in[4];
  const float* att_s  = (const float*)d_in[5];
  const float* att_n  = (const float*)d_in[6];
  const float* eps    = (const float*)d_in[7];
  const float* biases = (const float*)d_in[8];
  const float* att_b  = (const float*)d_in[9];

  // ws layout (~66 MB; ws >= 104 MB established in R3). G1 now separate (no alias).
  char* w = (char*)d_ws;
  short* WT      = (short*)(w);                      // [0,        131072)
  short* KhT     = (short*)(w + 131072);             // [131072,   655360)
  float* diag    = (float*)(w + 655360);             // [655360,   786432)
  unsigned* xbits= (unsigned*)(w + 786432);          // [786432,  1835008)
  short* atomb   = (short*)(w + 1835008);            // [1835008, 18612224)
  short* xbf     = (short*)(w + 18612224);           // [18612224, 35389440)
  short* G2nf    = (short*)(w + 35389440);           // [35389440, 52166656)
  short* G1      = (short*)(w + 52166656);           // [52166656, 68943872)

  float* out  = (float*)d_out;
  float* out2 = out + 33554432;  // B*N*H*D floats

  ktrans<<<dim3(8, 8, 5), 256, 0, stream>>>(fc_w, kers, WT, KhT);
  kprep<<<dim3(8, 128, 2), 256, 0, stream>>>(atom, x, atomb, xbf, xbits, diag);
  kG12<<<dim3(256), 512, 0, stream>>>(WT, atomb, xbf, G2nf, G1);
  kHead<<<dim3(512), 512, 0, stream>>>(KhT, G1, G2nf, diag, fc_b, eps,
                                       biases, att_s, att_n, att_b, xbits, out, out2);
}

// Round 15
// 164.791 us; speedup vs baseline: 1.3976x; 1.0388x over previous
//
#include <hip/hip_runtime.h>

typedef __attribute__((ext_vector_type(8))) short bf16x8;
typedef __attribute__((ext_vector_type(4))) short short4v;
typedef __attribute__((ext_vector_type(4))) float f32x4;

// B=128, N=256, D=256, H=4 ; per-batch matrices are [256][256] (65536 elems)

__device__ __forceinline__ float b2f(short s){
  unsigned u = ((unsigned)(unsigned short)s) << 16;
  return __builtin_bit_cast(float, u);
}
__device__ __forceinline__ short f2b(float f){
  unsigned u = __builtin_bit_cast(unsigned, f);
  u = (u + 0x7FFFu + ((u >> 16) & 1u)) >> 16;
  return (short)(unsigned short)u;
}

// XOR swizzle for 512B-stride rows: spread across the 8 16B-slot orbit.
#define SWZ(row, bytecol) ((((row) * 512) + (bytecol)) ^ (((row) & 7) << 4))

// -------- transpose-convert f32 [256][256] -> bf16 ^T : z=0 fc_w->WT, z=1..4 kernels->KhT --------
__global__ __launch_bounds__(256) void ktrans(const float* __restrict__ fcw, const float* __restrict__ kers,
                                              short* __restrict__ WT, short* __restrict__ KhT){
  __shared__ float tile[32][33];
  int z = blockIdx.z;
  const float* src = (z == 0) ? fcw : (kers + (z-1)*65536);
  short* dst = (z == 0) ? WT : (KhT + (z-1)*65536);
  int x0 = blockIdx.x*32, y0 = blockIdx.y*32;
  int tx = threadIdx.x & 31, ty = threadIdx.x >> 5;
  #pragma unroll
  for (int i = 0; i < 32; i += 8) tile[ty+i][tx] = src[(y0+ty+i)*256 + x0+tx];
  __syncthreads();
  #pragma unroll
  for (int i = 0; i < 32; i += 8) dst[(x0+ty+i)*256 + y0+tx] = f2b(tile[tx][ty+i]);
}

// -------- prep: z=0 atom f32->bf16 ; z=1 x f32->bf16 + bitfields + diag. grid (8,128,2) --------
__global__ __launch_bounds__(256) void kprep(const float* __restrict__ atom, const float* __restrict__ x,
                                             short* __restrict__ atom_bf, short* __restrict__ xbf,
                                             unsigned* __restrict__ xbits, float* __restrict__ diag){
  int b = blockIdx.y;
  int row = blockIdx.x*32 + (threadIdx.x >> 3);
  int seg = threadIdx.x & 7;
  if (blockIdx.z == 0){
    const float* p = atom + b*65536 + row*256 + seg*32;
    short* q = atom_bf + b*65536 + row*256 + seg*32;
    #pragma unroll
    for (int k = 0; k < 4; k++){
      f32x4 a = ((const f32x4*)p)[k*2], c = ((const f32x4*)p)[k*2+1];
      bf16x8 o;
      #pragma unroll
      for (int e = 0; e < 4; e++){ o[e] = f2b(a[e]); o[4+e] = f2b(c[e]); }
      ((bf16x8*)q)[k] = o;
    }
  } else {
    const float* p = x + b*65536 + row*256 + seg*32;
    float v[32];
    #pragma unroll
    for (int k = 0; k < 8; k++){
      f32x4 qv = ((const f32x4*)p)[k];
      #pragma unroll
      for (int e = 0; e < 4; e++) v[k*4+e] = qv[e];
    }
    unsigned bits = 0u;
    #pragma unroll
    for (int e = 0; e < 32; e++) if (v[e] > 0.5f) bits |= (1u << e);
    xbits[(b*256 + row)*8 + seg] = bits;
    short* q = xbf + b*65536 + row*256 + seg*32;
    #pragma unroll
    for (int k = 0; k < 4; k++){
      bf16x8 o;
      #pragma unroll
      for (int e = 0; e < 8; e++) o[e] = f2b(v[k*8+e]);
      ((bf16x8*)q)[k] = o;
    }
    if ((row >> 5) == seg) diag[b*256 + row] = v[row & 31];
  }
}

// ======== kG12: per (b, f-half) — G2-half = atom@W into LDS (G2T layout) + G2nf global,
//          then G1-half = x@G2 from LDS. grid 256, 512 thr, one barrier. ========
__global__ __launch_bounds__(512, 1) void kG12(const short* __restrict__ WT, const short* __restrict__ atomb,
                                               const short* __restrict__ xbf,
                                               short* __restrict__ G2nf, short* __restrict__ G1){
  __shared__ __align__(16) char G2s[65536];   // [128 f-local][256 m] bf16, SWZ
  int wg = blockIdx.x;                 // 0..255
  int xcd = wg & 7, idx = wg >> 3;     // idx 0..31
  int b  = xcd + ((idx >> 1) << 3);    // 16 batches per xcd
  int fh = idx & 1;
  int tid = threadIdx.x, lane = tid & 63, w = tid >> 6;
  int lr = lane & 15, lq = lane >> 4, koff = lq * 8;

  // ---- GEMM1: D[m][f-local] = atom @ W-half ; waves 4m x 2f ----
  {
    int wm = (w >> 1) * 64, wf = (w & 1) * 64;
    const short* Ab = atomb + b*65536;
    const short* Bw = WT + (fh*128 + wf)*256;
    f32x4 acc[4][4] = {};
    for (int k0 = 0; k0 < 256; k0 += 32){
      bf16x8 af[4], bfr[4];
      #pragma unroll
      for (int i = 0; i < 4; i++) af[i]  = *(const bf16x8*)(Ab + (wm + i*16 + lr)*256 + k0 + koff);
      #pragma unroll
      for (int j = 0; j < 4; j++) bfr[j] = *(const bf16x8*)(Bw + (j*16 + lr)*256 + k0 + koff);
      #pragma unroll
      for (int i = 0; i < 4; i++)
        #pragma unroll
        for (int j = 0; j < 4; j++)
          acc[i][j] = __builtin_amdgcn_mfma_f32_16x16x32_bf16(af[i], bfr[j], acc[i][j], 0, 0, 0);
    }
    // m = wm + i*16 + lq*4 + r (reg-dim), f_local = wf + j*16 + lr (lane-dim)
    #pragma unroll
    for (int i = 0; i < 4; i++)
      #pragma unroll
      for (int j = 0; j < 4; j++){
        short4v v;
        #pragma unroll
        for (int r = 0; r < 4; r++) v[r] = f2b(acc[i][j][r]);
        int fl = wf + j*16 + lr;
        int m0 = wm + i*16 + lq*4;
        *(short4v*)(G2s + SWZ(fl, m0*2)) = v;                          // LDS G2T[f][m] 8B
        #pragma unroll
        for (int r = 0; r < 4; r++)
          G2nf[b*65536 + (m0 + r)*256 + fh*128 + fl] = v[r];           // global [m][f]
      }
  }
  __syncthreads();

  // ---- GEMM2: D[f-local][n] = G2T-LDS @ x ; waves 2f x 4n ----
  {
    int wf2 = (w >> 2) * 64, wn2 = (w & 3) * 64;
    const short* Xb = xbf + b*65536;
    f32x4 acc[4][4] = {};
    for (int k0 = 0; k0 < 256; k0 += 32){
      bf16x8 af[4], bfr[4];
      #pragma unroll
      for (int i = 0; i < 4; i++) af[i]  = *(const bf16x8*)(G2s + SWZ(wf2 + i*16 + lr, (k0 + koff)*2));
      #pragma unroll
      for (int j = 0; j < 4; j++) bfr[j] = *(const bf16x8*)(Xb + (wn2 + j*16 + lr)*256 + k0 + koff);
      #pragma unroll
      for (int i = 0; i < 4; i++)
        #pragma unroll
        for (int j = 0; j < 4; j++)
          acc[i][j] = __builtin_amdgcn_mfma_f32_16x16x32_bf16(af[i], bfr[j], acc[i][j], 0, 0, 0);
    }
    // C^T: n = wn2 + j*16 + lr (lane), f = fh*128 + wf2 + i*16 + lq*4 + r (reg)
    #pragma unroll
    for (int i = 0; i < 4; i++)
      #pragma unroll
      for (int j = 0; j < 4; j++){
        short4v v;
        #pragma unroll
        for (int r = 0; r < 4; r++) v[r] = f2b(acc[i][j][r]);
        *(short4v*)(G1 + b*65536 + (wn2 + j*16 + lr)*256 + fh*128 + wf2 + i*16 + lq*4) = v;
      }
  }
}

// ======== kHead: per (h,b) — K in LDS, shared-h1s phase 1 (R13 structure, best measured),
//          swapped epilogue -> featS, xbits staged, overlapped softmax/PV phase 2. ========
__global__ __launch_bounds__(512, 1) void kHead(const short* __restrict__ KhT, const short* __restrict__ G1,
                                                const short* __restrict__ G2nf, const float* __restrict__ diag,
                                                const float* __restrict__ fcb, const float* __restrict__ epsv,
                                                const float* __restrict__ biases, const float* __restrict__ atts,
                                                const float* __restrict__ attn, const float* __restrict__ attbv,
                                                const unsigned* __restrict__ xbits,
                                                float* __restrict__ out, float* __restrict__ out2){
  __shared__ __align__(16) char featS[131072];    // phase1: K[o][k] SWZ ; then feat^T[o][n] SWZ
  __shared__ __align__(16) char scratch[24576];   // h1s[256][40] | Pb0@0, Pb1@8192, red/xbitsL@16384
  __shared__ float asvL[256], anvL[256], fcbL[256];

  short (*h1s)[40] = (short(*)[40])scratch;
  char* Pb0 = scratch;
  char* Pb1 = scratch + 8192;
  float (*red_s)[64] = (float(*)[64])(scratch + 16384);
  float (*red_n)[64] = (float(*)[64])(scratch + 16384 + 2048);
  unsigned* xbitsL = (unsigned*)(scratch + 16384);

  int wg = blockIdx.x;
  int xcd = wg & 7, idx = wg >> 3;
  int b = xcd + ((idx >> 2) << 3);   // 16 batches per xcd, 4 heads adjacent
  int h = idx & 3;
  int tid = threadIdx.x, lane = tid & 63, w = tid >> 6;
  float epsm1 = epsv[h] - 1.0f;
  const short* KA  = KhT + h*65536;
  const short* G1b = G1  + b*65536;
  const short* G2b = G2nf + b*65536;

  // ---- stage K (128 KB) into featS, SWZ[o][k]; stage fcb ----
  {
    int o = tid >> 1, half = (tid & 1) * 128;
    #pragma unroll
    for (int q = 0; q < 16; q++){
      int kk = half + q*8;
      bf16x8 v = *(const bf16x8*)(KA + o*256 + kk);
      *(bf16x8*)(featS + SWZ(o, kk*2)) = v;
    }
    if (tid < 256) fcbL[tid] = fcb[tid];
  }

  // rebuild assignment: thread -> (row nl 0..255, 16-k half)
  int nl = tid >> 1, rkk = (tid & 1) * 16;
  float cj = epsm1 * diag[b*256 + nl];

  // wave geometry (phase 1)
  int wro = (w >> 2) * 128;   // o-half
  int wn  = (w & 3) * 64;     // n-quarter
  int lr = lane & 15, lq = lane >> 4;
  int koff = lq * 8;

  // prefetch G1/G2 for k-step 0
  bf16x8 p1a = *(const bf16x8*)(G1b + nl*256 + rkk);
  bf16x8 p1b = *(const bf16x8*)(G1b + nl*256 + rkk + 8);
  bf16x8 p2a = *(const bf16x8*)(G2b + nl*256 + rkk);
  bf16x8 p2b = *(const bf16x8*)(G2b + nl*256 + rkk + 8);

  __syncthreads();   // K + fcb staged

  // ---------------- phase 1: feat = h1 @ K_h (shared h1s rebuild, acc[j_n][i_o]) ----------------
  f32x4 acc[4][8] = {};
  for (int t = 0; t < 8; t++){
    int k0 = t*32;
    {
      bf16x8 o1, o2;
      #pragma unroll
      for (int e = 0; e < 8; e++){
        float v = b2f(p1a[e]) + cj*b2f(p2a[e]) + fcbL[k0 + rkk + e];
        v = v > 0.f ? v : 0.01f*v;
        o1[e] = f2b(v);
      }
      #pragma unroll
      for (int e = 0; e < 8; e++){
        float v = b2f(p1b[e]) + cj*b2f(p2b[e]) + fcbL[k0 + rkk + 8 + e];
        v = v > 0.f ? v : 0.01f*v;
        o2[e] = f2b(v);
      }
      *(bf16x8*)&h1s[nl][rkk] = o1;
      *(bf16x8*)&h1s[nl][rkk + 8] = o2;
    }
    __syncthreads();
    if (t < 7){
      int kn = k0 + 32;
      p1a = *(const bf16x8*)(G1b + nl*256 + kn + rkk);
      p1b = *(const bf16x8*)(G1b + nl*256 + kn + rkk + 8);
      p2a = *(const bf16x8*)(G2b + nl*256 + kn + rkk);
      p2b = *(const bf16x8*)(G2b + nl*256 + kn + rkk + 8);
    }
    bf16x8 af[4];
    #pragma unroll
    for (int j = 0; j < 4; j++) af[j] = *(const bf16x8*)&h1s[wn + j*16 + lr][koff];
    #pragma unroll
    for (int i = 0; i < 8; i++){
      bf16x8 bfv = *(const bf16x8*)(featS + SWZ(wro + i*16 + lr, (k0 + koff)*2));
      #pragma unroll
      for (int j = 0; j < 4; j++)
        acc[j][i] = __builtin_amdgcn_mfma_f32_16x16x32_bf16(af[j], bfv, acc[j][i], 0, 0, 0);
    }
    __syncthreads();
  }

  // ---------------- epilogue: bias + vectorized feat^T stores + a_s/a_n partials ----------------
  float ps[4][4] = {}, pn[4][4] = {};
  #pragma unroll
  for (int i = 0; i < 8; i++){
    int od = wro + i*16 + lr;                       // o (lane-dim)
    float bi  = biases[h*256 + od];
    float wsv = atts[h*256 + od];
    float wnv = attn[h*256 + od];
    #pragma unroll
    for (int j = 0; j < 4; j++){
      short4v sv;
      #pragma unroll
      for (int r = 0; r < 4; r++){
        float fv = acc[j][i][r] + bi;
        sv[r] = f2b(fv);
        ps[j][r] += fv * wsv;
        pn[j][r] += fv * wnv;
      }
      *(short4v*)(featS + SWZ(od, (wn + j*16 + lq*4)*2) ) = sv;   // 8B store
    }
  }
  #pragma unroll
  for (int j = 0; j < 4; j++)
    #pragma unroll
    for (int r = 0; r < 4; r++){
      float s = ps[j][r], nv = pn[j][r];
      s += __shfl_xor(s, 1); s += __shfl_xor(s, 2); s += __shfl_xor(s, 4); s += __shfl_xor(s, 8);
      nv += __shfl_xor(nv, 1); nv += __shfl_xor(nv, 2); nv += __shfl_xor(nv, 4); nv += __shfl_xor(nv, 8);
      ps[j][r] = s; pn[j][r] = nv;
    }
  __syncthreads();            // h1s reads done -> red overlay safe
  if (lr == 0){
    #pragma unroll
    for (int j = 0; j < 4; j++)
      #pragma unroll
      for (int r = 0; r < 4; r++){
        red_s[w][j*16 + lq*4 + r] = ps[j][r];
        red_n[w][j*16 + lq*4 + r] = pn[j][r];
      }
  }
  __syncthreads();
  if (tid < 256){
    int q = tid >> 6, nn = tid & 63;
    asvL[tid] = red_s[q][nn] + red_s[q+4][nn] + attbv[h];
    anvL[tid] = red_n[q][nn] + red_n[q+4][nn];
  }
  __syncthreads();   // red consumed -> xbitsL overlay safe
  {
    const unsigned* xb = xbits + b*2048;
    #pragma unroll
    for (int q = 0; q < 4; q++) xbitsL[tid*4 + q] = xb[tid*4 + q];
  }
  __syncthreads();

  // ---------------- phase 2: 16 passes, PV(t) overlapped with softmax(t+1) ----------------
  int row = tid >> 5, seg = tid & 31;
  {
    int i = row;
    float as_i = asvL[i];
    unsigned bits = xbitsL[i*8 + (seg >> 2)];
    int sh = (seg & 3) * 8;
    float Lv[8]; float mx = -3.0e38f;
    #pragma unroll
    for (int e = 0; e < 8; e++){
      float s = as_i + anvL[seg*8 + e];
      float el = s > 0.f ? s : (__expf(s) - 1.0f);
      float L = el + (((bits >> (sh + e)) & 1u) ? 0.f : -1.0e10f);
      Lv[e] = L; mx = fmaxf(mx, L);
    }
    mx = fmaxf(mx, __shfl_xor(mx, 1)); mx = fmaxf(mx, __shfl_xor(mx, 2));
    mx = fmaxf(mx, __shfl_xor(mx, 4)); mx = fmaxf(mx, __shfl_xor(mx, 8));
    mx = fmaxf(mx, __shfl_xor(mx, 16));
    float sum = 0.f;
    #pragma unroll
    for (int e = 0; e < 8; e++){ float p = __expf(Lv[e] - mx); Lv[e] = p; sum += p; }
    sum += __shfl_xor(sum, 1); sum += __shfl_xor(sum, 2); sum += __shfl_xor(sum, 4);
    sum += __shfl_xor(sum, 8); sum += __shfl_xor(sum, 16);
    float inv = 1.0f / sum;
    bf16x8 pv;
    #pragma unroll
    for (int e = 0; e < 8; e++) pv[e] = f2b(Lv[e] * inv);
    *(bf16x8*)(Pb0 + SWZ(row, seg*16)) = pv;
    if (h == 3){
      float* o2 = out2 + b*65536 + i*256 + seg*8;
      f32x4 v0, v1;
      #pragma unroll
      for (int e = 0; e < 4; e++){ v0[e] = Lv[e]*inv; v1[e] = Lv[4+e]*inv; }
      *(f32x4*)(o2) = v0; *(f32x4*)(o2 + 4) = v1;
    }
  }

  int o0w = w * 32;
  for (int t = 0; t < 16; t++){
    __syncthreads();
    int it0 = t * 16;
    char* Pr = (t & 1) ? Pb1 : Pb0;
    f32x4 a2[2] = {};
    for (int k0 = 0; k0 < 256; k0 += 32){
      bf16x8 bfp = *(const bf16x8*)(Pr + SWZ(lr, (k0 + koff)*2));
      #pragma unroll
      for (int ii = 0; ii < 2; ii++){
        bf16x8 afv = *(const bf16x8*)(featS + SWZ(o0w + ii*16 + lr, (k0 + koff)*2));
        a2[ii] = __builtin_amdgcn_mfma_f32_16x16x32_bf16(afv, bfp, a2[ii], 0, 0, 0);
      }
    }
    #pragma unroll
    for (int ii = 0; ii < 2; ii++)
      *(f32x4*)(out + (size_t)(b*256 + it0 + lr)*1024 + h*256 + o0w + ii*16 + lq*4) = a2[ii];

    if (t < 15){
      char* Pw = (t & 1) ? Pb0 : Pb1;
      int i = it0 + 16 + row;
      float as_i = asvL[i];
      unsigned bits = xbitsL[i*8 + (seg >> 2)];
      int sh = (seg & 3) * 8;
      float Lv[8]; float mx = -3.0e38f;
      #pragma unroll
      for (int e = 0; e < 8; e++){
        float s = as_i + anvL[seg*8 + e];
        float el = s > 0.f ? s : (__expf(s) - 1.0f);
        float L = el + (((bits >> (sh + e)) & 1u) ? 0.f : -1.0e10f);
        Lv[e] = L; mx = fmaxf(mx, L);
      }
      mx = fmaxf(mx, __shfl_xor(mx, 1)); mx = fmaxf(mx, __shfl_xor(mx, 2));
      mx = fmaxf(mx, __shfl_xor(mx, 4)); mx = fmaxf(mx, __shfl_xor(mx, 8));
      mx = fmaxf(mx, __shfl_xor(mx, 16));
      float sum = 0.f;
      #pragma unroll
      for (int e = 0; e < 8; e++){ float p = __expf(Lv[e] - mx); Lv[e] = p; sum += p; }
      sum += __shfl_xor(sum, 1); sum += __shfl_xor(sum, 2); sum += __shfl_xor(sum, 4);
      sum += __shfl_xor(sum, 8); sum += __shfl_xor(sum, 16);
      float inv = 1.0f / sum;
      bf16x8 pv;
      #pragma unroll
      for (int e = 0; e < 8; e++) pv[e] = f2b(Lv[e] * inv);
      *(bf16x8*)(Pw + SWZ(row, seg*16)) = pv;
      if (h == 3){
        float* o2 = out2 + b*65536 + i*256 + seg*8;
        f32x4 v0, v1;
        #pragma unroll
        for (int e = 0; e < 4; e++){ v0[e] = Lv[e]*inv; v1[e] = Lv[4+e]*inv; }
        *(f32x4*)(o2) = v0; *(f32x4*)(o2 + 4) = v1;
      }
    }
  }
}

extern "C" void kernel_launch(void* const* d_in, const int* in_sizes, int n_in,
                              void* d_out, int out_size, void* d_ws, size_t ws_size,
                              hipStream_t stream) {
  const float* atom   = (const float*)d_in[0];
  const float* x      = (const float*)d_in[1];
  const float* fc_w   = (const float*)d_in[2];
  const float* fc_b   = (const float*)d_in[3];
  const float* kers   = (const float*)d_in[4];
  const float* att_s  = (const float*)d_in[5];
  const float* att_n  = (const float*)d_in[6];
  const float* eps    = (const float*)d_in[7];
  const float* biases = (const float*)d_in[8];
  const float* att_b  = (const float*)d_in[9];

  // ws layout (~66 MB; ws >= 104 MB established in R3).
  char* w = (char*)d_ws;
  short* WT      = (short*)(w);                      // [0,        131072)
  short* KhT     = (short*)(w + 131072);             // [131072,   655360)
  float* diag    = (float*)(w + 655360);             // [655360,   786432)
  unsigned* xbits= (unsigned*)(w + 786432);          // [786432,  1835008)
  short* atomb   = (short*)(w + 1835008);            // [1835008, 18612224)
  short* xbf     = (short*)(w + 18612224);           // [18612224, 35389440)
  short* G2nf    = (short*)(w + 35389440);           // [35389440, 52166656)
  short* G1      = (short*)(w + 52166656);           // [52166656, 68943872)

  float* out  = (float*)d_out;
  float* out2 = out + 33554432;  // B*N*H*D floats

  ktrans<<<dim3(8, 8, 5), 256, 0, stream>>>(fc_w, kers, WT, KhT);
  kprep<<<dim3(8, 128, 2), 256, 0, stream>>>(atom, x, atomb, xbf, xbits, diag);
  kG12<<<dim3(256), 512, 0, stream>>>(WT, atomb, xbf, G2nf, G1);
  kHead<<<dim3(512), 512, 0, stream>>>(KhT, G1, G2nf, diag, fc_b, eps,
                                       biases, att_s, att_n, att_b, xbits, out, out2);
}

// Round 16
// 162.683 us; speedup vs baseline: 1.4158x; 1.0130x over previous
//
#include <hip/hip_runtime.h>

typedef __attribute__((ext_vector_type(8))) short bf16x8;
typedef __attribute__((ext_vector_type(4))) short short4v;
typedef __attribute__((ext_vector_type(4))) float f32x4;

// B=128, N=256, D=256, H=4 ; per-batch matrices are [256][256] (65536 elems)

__device__ __forceinline__ float b2f(short s){
  unsigned u = ((unsigned)(unsigned short)s) << 16;
  return __builtin_bit_cast(float, u);
}
__device__ __forceinline__ short f2b(float f){
  unsigned u = __builtin_bit_cast(unsigned, f);
  u = (u + 0x7FFFu + ((u >> 16) & 1u)) >> 16;
  return (short)(unsigned short)u;
}

// XOR swizzle for 512B-stride rows: spread across the 8 16B-slot orbit.
#define SWZ(row, bytecol) ((((row) * 512) + (bytecol)) ^ (((row) & 7) << 4))

// -------- transpose-convert f32 [256][256] -> bf16 ^T : z=0 fc_w->WT, z=1..4 kernels->KhT --------
__global__ __launch_bounds__(256) void ktrans(const float* __restrict__ fcw, const float* __restrict__ kers,
                                              short* __restrict__ WT, short* __restrict__ KhT){
  __shared__ float tile[32][33];
  int z = blockIdx.z;
  const float* src = (z == 0) ? fcw : (kers + (z-1)*65536);
  short* dst = (z == 0) ? WT : (KhT + (z-1)*65536);
  int x0 = blockIdx.x*32, y0 = blockIdx.y*32;
  int tx = threadIdx.x & 31, ty = threadIdx.x >> 5;
  #pragma unroll
  for (int i = 0; i < 32; i += 8) tile[ty+i][tx] = src[(y0+ty+i)*256 + x0+tx];
  __syncthreads();
  #pragma unroll
  for (int i = 0; i < 32; i += 8) dst[(x0+ty+i)*256 + y0+tx] = f2b(tile[tx][ty+i]);
}

// ======== kG12: per (b, f-half) — GEMM1 = atom(f32,inline-cvt) @ W-half -> LDS G2T + G2nf;
//          GEMM2 = G2T-LDS @ x(f32,inline-cvt, xbits/diag on the fly) -> G1. grid 256. ========
__global__ __launch_bounds__(512, 1) void kG12(const short* __restrict__ WT, const float* __restrict__ atom,
                                               const float* __restrict__ x,
                                               short* __restrict__ G2nf, short* __restrict__ G1,
                                               unsigned* __restrict__ xbits, float* __restrict__ diag){
  __shared__ __align__(16) char G2s[65536];   // [128 f-local][256 m] bf16, SWZ
  int wg = blockIdx.x;                 // 0..255
  int xcd = wg & 7, idx = wg >> 3;     // idx 0..31
  int b  = xcd + ((idx >> 1) << 3);    // 16 batches per xcd
  int fh = idx & 1;
  int tid = threadIdx.x, lane = tid & 63, w = tid >> 6;
  int lr = lane & 15, lq = lane >> 4, koff = lq * 8;

  // ---- GEMM1: D[m][f-local] = atom @ W-half ; waves 4m x 2f ; A converted inline ----
  {
    int wm = (w >> 1) * 64, wf = (w & 1) * 64;
    const float* Ab = atom + b*65536;
    const short* Bw = WT + (fh*128 + wf)*256;
    f32x4 acc[4][4] = {};
    for (int k0 = 0; k0 < 256; k0 += 32){
      bf16x8 af[4], bfr[4];
      #pragma unroll
      for (int i = 0; i < 4; i++){
        const float* p = Ab + (wm + i*16 + lr)*256 + k0 + koff;
        f32x4 a0 = *(const f32x4*)p, a1 = *(const f32x4*)(p + 4);
        #pragma unroll
        for (int e = 0; e < 4; e++){ af[i][e] = f2b(a0[e]); af[i][4+e] = f2b(a1[e]); }
      }
      #pragma unroll
      for (int j = 0; j < 4; j++) bfr[j] = *(const bf16x8*)(Bw + (j*16 + lr)*256 + k0 + koff);
      #pragma unroll
      for (int i = 0; i < 4; i++)
        #pragma unroll
        for (int j = 0; j < 4; j++)
          acc[i][j] = __builtin_amdgcn_mfma_f32_16x16x32_bf16(af[i], bfr[j], acc[i][j], 0, 0, 0);
    }
    // m = wm + i*16 + lq*4 + r (reg-dim), f_local = wf + j*16 + lr (lane-dim)
    #pragma unroll
    for (int i = 0; i < 4; i++)
      #pragma unroll
      for (int j = 0; j < 4; j++){
        short4v v;
        #pragma unroll
        for (int r = 0; r < 4; r++) v[r] = f2b(acc[i][j][r]);
        int fl = wf + j*16 + lr;
        int m0 = wm + i*16 + lq*4;
        *(short4v*)(G2s + SWZ(fl, m0*2)) = v;                          // LDS G2T[f][m] 8B
        #pragma unroll
        for (int r = 0; r < 4; r++)
          G2nf[b*65536 + (m0 + r)*256 + fh*128 + fl] = v[r];           // global [m][f]
      }
  }
  __syncthreads();

  // ---- GEMM2: D[f-local][n] = G2T-LDS @ x ; waves 2f x 4n ; B converted inline + xbits/diag ----
  {
    int wf2 = (w >> 2) * 64, wn2 = (w & 3) * 64;
    const float* Xb = x + b*65536;
    f32x4 acc[4][4] = {};
    for (int k0 = 0; k0 < 256; k0 += 32){
      bf16x8 af[4], bfr[4];
      #pragma unroll
      for (int i = 0; i < 4; i++) af[i]  = *(const bf16x8*)(G2s + SWZ(wf2 + i*16 + lr, (k0 + koff)*2));
      #pragma unroll
      for (int j = 0; j < 4; j++){
        int n = wn2 + j*16 + lr;
        const float* p = Xb + n*256 + k0 + koff;
        f32x4 x0 = *(const f32x4*)p, x1 = *(const f32x4*)(p + 4);
        unsigned b8 = 0u;
        #pragma unroll
        for (int e = 0; e < 4; e++){
          bfr[j][e] = f2b(x0[e]);     if (x0[e] > 0.5f) b8 |= (1u << e);
          bfr[j][4+e] = f2b(x1[e]);   if (x1[e] > 0.5f) b8 |= (1u << (4 + e));
        }
        if (w < 4){   // waves 0-3 cover each n exactly once
          unsigned full = b8 << (lq * 8);
          full |= __shfl_xor(full, 16);
          full |= __shfl_xor(full, 32);
          if (lq == 0) xbits[(b*256 + n)*8 + (k0 >> 5)] = full;
          int nm = n & 31;
          if ((n & ~31) == k0 && (nm >> 3) == lq)
            diag[b*256 + n] = (nm & 4) ? x1[nm & 3] : x0[nm & 3];
        }
      }
      #pragma unroll
      for (int i = 0; i < 4; i++)
        #pragma unroll
        for (int j = 0; j < 4; j++)
          acc[i][j] = __builtin_amdgcn_mfma_f32_16x16x32_bf16(af[i], bfr[j], acc[i][j], 0, 0, 0);
    }
    // C^T: n = wn2 + j*16 + lr (lane), f = fh*128 + wf2 + i*16 + lq*4 + r (reg)
    #pragma unroll
    for (int i = 0; i < 4; i++)
      #pragma unroll
      for (int j = 0; j < 4; j++){
        short4v v;
        #pragma unroll
        for (int r = 0; r < 4; r++) v[r] = f2b(acc[i][j][r]);
        *(short4v*)(G1 + b*65536 + (wn2 + j*16 + lr)*256 + fh*128 + wf2 + i*16 + lq*4) = v;
      }
  }
}

// ======== kHead: per (h,b) — K in LDS, shared-h1s phase 1, swapped epilogue -> featS,
//          xbits staged, overlapped softmax/PV phase 2. (R15 structure, unchanged) ========
__global__ __launch_bounds__(512, 1) void kHead(const short* __restrict__ KhT, const short* __restrict__ G1,
                                                const short* __restrict__ G2nf, const float* __restrict__ diag,
                                                const float* __restrict__ fcb, const float* __restrict__ epsv,
                                                const float* __restrict__ biases, const float* __restrict__ atts,
                                                const float* __restrict__ attn, const float* __restrict__ attbv,
                                                const unsigned* __restrict__ xbits,
                                                float* __restrict__ out, float* __restrict__ out2){
  __shared__ __align__(16) char featS[131072];    // phase1: K[o][k] SWZ ; then feat^T[o][n] SWZ
  __shared__ __align__(16) char scratch[24576];   // h1s[256][40] | Pb0@0, Pb1@8192, red/xbitsL@16384
  __shared__ float asvL[256], anvL[256], fcbL[256];

  short (*h1s)[40] = (short(*)[40])scratch;
  char* Pb0 = scratch;
  char* Pb1 = scratch + 8192;
  float (*red_s)[64] = (float(*)[64])(scratch + 16384);
  float (*red_n)[64] = (float(*)[64])(scratch + 16384 + 2048);
  unsigned* xbitsL = (unsigned*)(scratch + 16384);

  int wg = blockIdx.x;
  int xcd = wg & 7, idx = wg >> 3;
  int b = xcd + ((idx >> 2) << 3);   // 16 batches per xcd, 4 heads adjacent
  int h = idx & 3;
  int tid = threadIdx.x, lane = tid & 63, w = tid >> 6;
  float epsm1 = epsv[h] - 1.0f;
  const short* KA  = KhT + h*65536;
  const short* G1b = G1  + b*65536;
  const short* G2b = G2nf + b*65536;

  // ---- stage K (128 KB) into featS, SWZ[o][k]; stage fcb ----
  {
    int o = tid >> 1, half = (tid & 1) * 128;
    #pragma unroll
    for (int q = 0; q < 16; q++){
      int kk = half + q*8;
      bf16x8 v = *(const bf16x8*)(KA + o*256 + kk);
      *(bf16x8*)(featS + SWZ(o, kk*2)) = v;
    }
    if (tid < 256) fcbL[tid] = fcb[tid];
  }

  // rebuild assignment: thread -> (row nl 0..255, 16-k half)
  int nl = tid >> 1, rkk = (tid & 1) * 16;
  float cj = epsm1 * diag[b*256 + nl];

  // wave geometry (phase 1)
  int wro = (w >> 2) * 128;   // o-half
  int wn  = (w & 3) * 64;     // n-quarter
  int lr = lane & 15, lq = lane >> 4;
  int koff = lq * 8;

  // prefetch G1/G2 for k-step 0
  bf16x8 p1a = *(const bf16x8*)(G1b + nl*256 + rkk);
  bf16x8 p1b = *(const bf16x8*)(G1b + nl*256 + rkk + 8);
  bf16x8 p2a = *(const bf16x8*)(G2b + nl*256 + rkk);
  bf16x8 p2b = *(const bf16x8*)(G2b + nl*256 + rkk + 8);

  __syncthreads();   // K + fcb staged

  // ---------------- phase 1: feat = h1 @ K_h (shared h1s rebuild, acc[j_n][i_o]) ----------------
  f32x4 acc[4][8] = {};
  for (int t = 0; t < 8; t++){
    int k0 = t*32;
    {
      bf16x8 o1, o2;
      #pragma unroll
      for (int e = 0; e < 8; e++){
        float v = b2f(p1a[e]) + cj*b2f(p2a[e]) + fcbL[k0 + rkk + e];
        v = v > 0.f ? v : 0.01f*v;
        o1[e] = f2b(v);
      }
      #pragma unroll
      for (int e = 0; e < 8; e++){
        float v = b2f(p1b[e]) + cj*b2f(p2b[e]) + fcbL[k0 + rkk + 8 + e];
        v = v > 0.f ? v : 0.01f*v;
        o2[e] = f2b(v);
      }
      *(bf16x8*)&h1s[nl][rkk] = o1;
      *(bf16x8*)&h1s[nl][rkk + 8] = o2;
    }
    __syncthreads();
    if (t < 7){
      int kn = k0 + 32;
      p1a = *(const bf16x8*)(G1b + nl*256 + kn + rkk);
      p1b = *(const bf16x8*)(G1b + nl*256 + kn + rkk + 8);
      p2a = *(const bf16x8*)(G2b + nl*256 + kn + rkk);
      p2b = *(const bf16x8*)(G2b + nl*256 + kn + rkk + 8);
    }
    bf16x8 af[4];
    #pragma unroll
    for (int j = 0; j < 4; j++) af[j] = *(const bf16x8*)&h1s[wn + j*16 + lr][koff];
    #pragma unroll
    for (int i = 0; i < 8; i++){
      bf16x8 bfv = *(const bf16x8*)(featS + SWZ(wro + i*16 + lr, (k0 + koff)*2));
      #pragma unroll
      for (int j = 0; j < 4; j++)
        acc[j][i] = __builtin_amdgcn_mfma_f32_16x16x32_bf16(af[j], bfv, acc[j][i], 0, 0, 0);
    }
    __syncthreads();
  }

  // ---------------- epilogue: bias + vectorized feat^T stores + a_s/a_n partials ----------------
  float ps[4][4] = {}, pn[4][4] = {};
  #pragma unroll
  for (int i = 0; i < 8; i++){
    int od = wro + i*16 + lr;                       // o (lane-dim)
    float bi  = biases[h*256 + od];
    float wsv = atts[h*256 + od];
    float wnv = attn[h*256 + od];
    #pragma unroll
    for (int j = 0; j < 4; j++){
      short4v sv;
      #pragma unroll
      for (int r = 0; r < 4; r++){
        float fv = acc[j][i][r] + bi;
        sv[r] = f2b(fv);
        ps[j][r] += fv * wsv;
        pn[j][r] += fv * wnv;
      }
      *(short4v*)(featS + SWZ(od, (wn + j*16 + lq*4)*2) ) = sv;   // 8B store
    }
  }
  #pragma unroll
  for (int j = 0; j < 4; j++)
    #pragma unroll
    for (int r = 0; r < 4; r++){
      float s = ps[j][r], nv = pn[j][r];
      s += __shfl_xor(s, 1); s += __shfl_xor(s, 2); s += __shfl_xor(s, 4); s += __shfl_xor(s, 8);
      nv += __shfl_xor(nv, 1); nv += __shfl_xor(nv, 2); nv += __shfl_xor(nv, 4); nv += __shfl_xor(nv, 8);
      ps[j][r] = s; pn[j][r] = nv;
    }
  __syncthreads();            // h1s reads done -> red overlay safe
  if (lr == 0){
    #pragma unroll
    for (int j = 0; j < 4; j++)
      #pragma unroll
      for (int r = 0; r < 4; r++){
        red_s[w][j*16 + lq*4 + r] = ps[j][r];
        red_n[w][j*16 + lq*4 + r] = pn[j][r];
      }
  }
  __syncthreads();
  if (tid < 256){
    int q = tid >> 6, nn = tid & 63;
    asvL[tid] = red_s[q][nn] + red_s[q+4][nn] + attbv[h];
    anvL[tid] = red_n[q][nn] + red_n[q+4][nn];
  }
  __syncthreads();   // red consumed -> xbitsL overlay safe
  {
    const unsigned* xb = xbits + b*2048;
    #pragma unroll
    for (int q = 0; q < 4; q++) xbitsL[tid*4 + q] = xb[tid*4 + q];
  }
  __syncthreads();

  // ---------------- phase 2: 16 passes, PV(t) overlapped with softmax(t+1) ----------------
  int row = tid >> 5, seg = tid & 31;
  {
    int i = row;
    float as_i = asvL[i];
    unsigned bits = xbitsL[i*8 + (seg >> 2)];
    int sh = (seg & 3) * 8;
    float Lv[8]; float mx = -3.0e38f;
    #pragma unroll
    for (int e = 0; e < 8; e++){
      float s = as_i + anvL[seg*8 + e];
      float el = s > 0.f ? s : (__expf(s) - 1.0f);
      float L = el + (((bits >> (sh + e)) & 1u) ? 0.f : -1.0e10f);
      Lv[e] = L; mx = fmaxf(mx, L);
    }
    mx = fmaxf(mx, __shfl_xor(mx, 1)); mx = fmaxf(mx, __shfl_xor(mx, 2));
    mx = fmaxf(mx, __shfl_xor(mx, 4)); mx = fmaxf(mx, __shfl_xor(mx, 8));
    mx = fmaxf(mx, __shfl_xor(mx, 16));
    float sum = 0.f;
    #pragma unroll
    for (int e = 0; e < 8; e++){ float p = __expf(Lv[e] - mx); Lv[e] = p; sum += p; }
    sum += __shfl_xor(sum, 1); sum += __shfl_xor(sum, 2); sum += __shfl_xor(sum, 4);
    sum += __shfl_xor(sum, 8); sum += __shfl_xor(sum, 16);
    float inv = 1.0f / sum;
    bf16x8 pv;
    #pragma unroll
    for (int e = 0; e < 8; e++) pv[e] = f2b(Lv[e] * inv);
    *(bf16x8*)(Pb0 + SWZ(row, seg*16)) = pv;
    if (h == 3){
      float* o2 = out2 + b*65536 + i*256 + seg*8;
      f32x4 v0, v1;
      #pragma unroll
      for (int e = 0; e < 4; e++){ v0[e] = Lv[e]*inv; v1[e] = Lv[4+e]*inv; }
      *(f32x4*)(o2) = v0; *(f32x4*)(o2 + 4) = v1;
    }
  }

  int o0w = w * 32;
  for (int t = 0; t < 16; t++){
    __syncthreads();
    int it0 = t * 16;
    char* Pr = (t & 1) ? Pb1 : Pb0;
    f32x4 a2[2] = {};
    for (int k0 = 0; k0 < 256; k0 += 32){
      bf16x8 bfp = *(const bf16x8*)(Pr + SWZ(lr, (k0 + koff)*2));
      #pragma unroll
      for (int ii = 0; ii < 2; ii++){
        bf16x8 afv = *(const bf16x8*)(featS + SWZ(o0w + ii*16 + lr, (k0 + koff)*2));
        a2[ii] = __builtin_amdgcn_mfma_f32_16x16x32_bf16(afv, bfp, a2[ii], 0, 0, 0);
      }
    }
    #pragma unroll
    for (int ii = 0; ii < 2; ii++)
      *(f32x4*)(out + (size_t)(b*256 + it0 + lr)*1024 + h*256 + o0w + ii*16 + lq*4) = a2[ii];

    if (t < 15){
      char* Pw = (t & 1) ? Pb0 : Pb1;
      int i = it0 + 16 + row;
      float as_i = asvL[i];
      unsigned bits = xbitsL[i*8 + (seg >> 2)];
      int sh = (seg & 3) * 8;
      float Lv[8]; float mx = -3.0e38f;
      #pragma unroll
      for (int e = 0; e < 8; e++){
        float s = as_i + anvL[seg*8 + e];
        float el = s > 0.f ? s : (__expf(s) - 1.0f);
        float L = el + (((bits >> (sh + e)) & 1u) ? 0.f : -1.0e10f);
        Lv[e] = L; mx = fmaxf(mx, L);
      }
      mx = fmaxf(mx, __shfl_xor(mx, 1)); mx = fmaxf(mx, __shfl_xor(mx, 2));
      mx = fmaxf(mx, __shfl_xor(mx, 4)); mx = fmaxf(mx, __shfl_xor(mx, 8));
      mx = fmaxf(mx, __shfl_xor(mx, 16));
      float sum = 0.f;
      #pragma unroll
      for (int e = 0; e < 8; e++){ float p = __expf(Lv[e] - mx); Lv[e] = p; sum += p; }
      sum += __shfl_xor(sum, 1); sum += __shfl_xor(sum, 2); sum += __shfl_xor(sum, 4);
      sum += __shfl_xor(sum, 8); sum += __shfl_xor(sum, 16);
      float inv = 1.0f / sum;
      bf16x8 pv;
      #pragma unroll
      for (int e = 0; e < 8; e++) pv[e] = f2b(Lv[e] * inv);
      *(bf16x8*)(Pw + SWZ(row, seg*16)) = pv;
      if (h == 3){
        float* o2 = out2 + b*65536 + i*256 + seg*8;
        f32x4 v0, v1;
        #pragma unroll
        for (int e = 0; e < 4; e++){ v0[e] = Lv[e]*inv; v1[e] = Lv[4+e]*inv; }
        *(f32x4*)(o2) = v0; *(f32x4*)(o2 + 4) = v1;
      }
    }
  }
}

extern "C" void kernel_launch(void* const* d_in, const int* in_sizes, int n_in,
                              void* d_out, int out_size, void* d_ws, size_t ws_size,
                              hipStream_t stream) {
  const float* atom   = (const float*)d_in[0];
  const float* x      = (const float*)d_in[1];
  const float* fc_w   = (const float*)d_in[2];
  const float* fc_b   = (const float*)d_in[3];
  const float* kers   = (const float*)d_in[4];
  const float* att_s  = (const float*)d_in[5];
  const float* att_n  = (const float*)d_in[6];
  const float* eps    = (const float*)d_in[7];
  const float* biases = (const float*)d_in[8];
  const float* att_b  = (const float*)d_in[9];

  // ws layout (~34 MB)
  char* w = (char*)d_ws;
  short* WT      = (short*)(w);                      // [0,        131072)
  short* KhT     = (short*)(w + 131072);             // [131072,   655360)
  float* diag    = (float*)(w + 655360);             // [655360,   786432)
  unsigned* xbits= (unsigned*)(w + 786432);          // [786432,  1835008)
  short* G2nf    = (short*)(w + 1835008);            // [1835008, 18612224)
  short* G1      = (short*)(w + 18612224);           // [18612224, 35389440)

  float* out  = (float*)d_out;
  float* out2 = out + 33554432;  // B*N*H*D floats

  ktrans<<<dim3(8, 8, 5), 256, 0, stream>>>(fc_w, kers, WT, KhT);
  kG12<<<dim3(256), 512, 0, stream>>>(WT, atom, x, G2nf, G1, xbits, diag);
  kHead<<<dim3(512), 512, 0, stream>>>(KhT, G1, G2nf, diag, fc_b, eps,
                                       biases, att_s, att_n, att_b, xbits, out, out2);
}

// Round 17
// 145.216 us; speedup vs baseline: 1.5861x; 1.1203x over previous
//
#include <hip/hip_runtime.h>

typedef __attribute__((ext_vector_type(8))) short bf16x8;
typedef __attribute__((ext_vector_type(4))) short short4v;
typedef __attribute__((ext_vector_type(4))) float f32x4;

// B=128, N=256, D=256, H=4 ; per-batch matrices are [256][256] (65536 elems)

__device__ __forceinline__ float b2f(short s){
  unsigned u = ((unsigned)(unsigned short)s) << 16;
  return __builtin_bit_cast(float, u);
}
__device__ __forceinline__ short f2b(float f){
  unsigned u = __builtin_bit_cast(unsigned, f);
  u = (u + 0x7FFFu + ((u >> 16) & 1u)) >> 16;
  return (short)(unsigned short)u;
}

// XOR swizzle for 512B-stride rows: spread across the 8 16B-slot orbit.
#define SWZ(row, bytecol) ((((row) * 512) + (bytecol)) ^ (((row) & 7) << 4))

// -------- transpose-convert f32 [256][256] -> bf16 ^T : z=0 fc_w->WT, z=1..4 kernels->KhT --------
__global__ __launch_bounds__(256) void ktrans(const float* __restrict__ fcw, const float* __restrict__ kers,
                                              short* __restrict__ WT, short* __restrict__ KhT){
  __shared__ float tile[32][33];
  int z = blockIdx.z;
  const float* src = (z == 0) ? fcw : (kers + (z-1)*65536);
  short* dst = (z == 0) ? WT : (KhT + (z-1)*65536);
  int x0 = blockIdx.x*32, y0 = blockIdx.y*32;
  int tx = threadIdx.x & 31, ty = threadIdx.x >> 5;
  #pragma unroll
  for (int i = 0; i < 32; i += 8) tile[ty+i][tx] = src[(y0+ty+i)*256 + x0+tx];
  __syncthreads();
  #pragma unroll
  for (int i = 0; i < 32; i += 8) dst[(x0+ty+i)*256 + y0+tx] = f2b(tile[tx][ty+i]);
}

// ======== kG12: per (b, f-half) — GEMM1 = atom(f32,inline-cvt) @ W-half -> LDS G2T + G2nf;
//          GEMM2 = G2T-LDS @ x(f32,inline-cvt, xbits/diag on the fly) -> G1. grid 256. ========
__global__ __launch_bounds__(512, 1) void kG12(const short* __restrict__ WT, const float* __restrict__ atom,
                                               const float* __restrict__ x,
                                               short* __restrict__ G2nf, short* __restrict__ G1,
                                               unsigned* __restrict__ xbits, float* __restrict__ diag){
  __shared__ __align__(16) char G2s[65536];   // [128 f-local][256 m] bf16, SWZ
  int wg = blockIdx.x;                 // 0..255
  int xcd = wg & 7, idx = wg >> 3;     // idx 0..31
  int b  = xcd + ((idx >> 1) << 3);    // 16 batches per xcd
  int fh = idx & 1;
  int tid = threadIdx.x, lane = tid & 63, w = tid >> 6;
  int lr = lane & 15, lq = lane >> 4, koff = lq * 8;

  // ---- GEMM1: D[m][f-local] = atom @ W-half ; waves 4m x 2f ; A converted inline ----
  {
    int wm = (w >> 1) * 64, wf = (w & 1) * 64;
    const float* Ab = atom + b*65536;
    const short* Bw = WT + (fh*128 + wf)*256;
    f32x4 acc[4][4] = {};
    for (int k0 = 0; k0 < 256; k0 += 32){
      bf16x8 af[4], bfr[4];
      #pragma unroll
      for (int i = 0; i < 4; i++){
        const float* p = Ab + (wm + i*16 + lr)*256 + k0 + koff;
        f32x4 a0 = *(const f32x4*)p, a1 = *(const f32x4*)(p + 4);
        #pragma unroll
        for (int e = 0; e < 4; e++){ af[i][e] = f2b(a0[e]); af[i][4+e] = f2b(a1[e]); }
      }
      #pragma unroll
      for (int j = 0; j < 4; j++) bfr[j] = *(const bf16x8*)(Bw + (j*16 + lr)*256 + k0 + koff);
      #pragma unroll
      for (int i = 0; i < 4; i++)
        #pragma unroll
        for (int j = 0; j < 4; j++)
          acc[i][j] = __builtin_amdgcn_mfma_f32_16x16x32_bf16(af[i], bfr[j], acc[i][j], 0, 0, 0);
    }
    // m = wm + i*16 + lq*4 + r (reg-dim), f_local = wf + j*16 + lr (lane-dim)
    #pragma unroll
    for (int i = 0; i < 4; i++)
      #pragma unroll
      for (int j = 0; j < 4; j++){
        short4v v;
        #pragma unroll
        for (int r = 0; r < 4; r++) v[r] = f2b(acc[i][j][r]);
        int fl = wf + j*16 + lr;
        int m0 = wm + i*16 + lq*4;
        *(short4v*)(G2s + SWZ(fl, m0*2)) = v;                          // LDS G2T[f][m] 8B
        #pragma unroll
        for (int r = 0; r < 4; r++)
          G2nf[b*65536 + (m0 + r)*256 + fh*128 + fl] = v[r];           // global [m][f]
      }
  }
  __syncthreads();

  // ---- GEMM2: D[f-local][n] = G2T-LDS @ x ; waves 2f x 4n ; B converted inline + xbits/diag ----
  {
    int wf2 = (w >> 2) * 64, wn2 = (w & 3) * 64;
    const float* Xb = x + b*65536;
    f32x4 acc[4][4] = {};
    for (int k0 = 0; k0 < 256; k0 += 32){
      bf16x8 af[4], bfr[4];
      #pragma unroll
      for (int i = 0; i < 4; i++) af[i]  = *(const bf16x8*)(G2s + SWZ(wf2 + i*16 + lr, (k0 + koff)*2));
      #pragma unroll
      for (int j = 0; j < 4; j++){
        int n = wn2 + j*16 + lr;
        const float* p = Xb + n*256 + k0 + koff;
        f32x4 x0 = *(const f32x4*)p, x1 = *(const f32x4*)(p + 4);
        unsigned b8 = 0u;
        #pragma unroll
        for (int e = 0; e < 4; e++){
          bfr[j][e] = f2b(x0[e]);     if (x0[e] > 0.5f) b8 |= (1u << e);
          bfr[j][4+e] = f2b(x1[e]);   if (x1[e] > 0.5f) b8 |= (1u << (4 + e));
        }
        if (w < 4){   // waves 0-3 cover each n exactly once
          unsigned full = b8 << (lq * 8);
          full |= __shfl_xor(full, 16);
          full |= __shfl_xor(full, 32);
          if (lq == 0) xbits[(b*256 + n)*8 + (k0 >> 5)] = full;
          int nm = n & 31;
          if ((n & ~31) == k0 && (nm >> 3) == lq)
            diag[b*256 + n] = (nm & 4) ? x1[nm & 3] : x0[nm & 3];
        }
      }
      #pragma unroll
      for (int i = 0; i < 4; i++)
        #pragma unroll
        for (int j = 0; j < 4; j++)
          acc[i][j] = __builtin_amdgcn_mfma_f32_16x16x32_bf16(af[i], bfr[j], acc[i][j], 0, 0, 0);
    }
    // C^T: n = wn2 + j*16 + lr (lane), f = fh*128 + wf2 + i*16 + lq*4 + r (reg)
    #pragma unroll
    for (int i = 0; i < 4; i++)
      #pragma unroll
      for (int j = 0; j < 4; j++){
        short4v v;
        #pragma unroll
        for (int r = 0; r < 4; r++) v[r] = f2b(acc[i][j][r]);
        *(short4v*)(G1 + b*65536 + (wn2 + j*16 + lr)*256 + fh*128 + wf2 + i*16 + lq*4) = v;
      }
  }
}

// ======== kHead: per (h,b) — K in LDS, shared-h1s phase 1, swapped epilogue -> featS;
//          phase 2: wave-private in-register softmax (P = MFMA B-fragments), ZERO barriers. ========
__global__ __launch_bounds__(512, 1) void kHead(const short* __restrict__ KhT, const short* __restrict__ G1,
                                                const short* __restrict__ G2nf, const float* __restrict__ diag,
                                                const float* __restrict__ fcb, const float* __restrict__ epsv,
                                                const float* __restrict__ biases, const float* __restrict__ atts,
                                                const float* __restrict__ attn, const float* __restrict__ attbv,
                                                const unsigned* __restrict__ xbits,
                                                float* __restrict__ out, float* __restrict__ out2){
  __shared__ __align__(16) char featS[131072];    // phase1: K[o][k] SWZ ; then feat^T[o][n] SWZ
  __shared__ __align__(16) char scratch[24576];   // h1s[256][40] | post-phase1: red@0/2048, xbitsL@4096
  __shared__ float asvL[256], anvL[256], fcbL[256];

  short (*h1s)[40] = (short(*)[40])scratch;
  float (*red_s)[64] = (float(*)[64])(scratch);
  float (*red_n)[64] = (float(*)[64])(scratch + 2048);
  unsigned* xbitsL = (unsigned*)(scratch + 4096);

  int wg = blockIdx.x;
  int xcd = wg & 7, idx = wg >> 3;
  int b = xcd + ((idx >> 2) << 3);   // 16 batches per xcd, 4 heads adjacent
  int h = idx & 3;
  int tid = threadIdx.x, lane = tid & 63, w = tid >> 6;
  float epsm1 = epsv[h] - 1.0f;
  const short* KA  = KhT + h*65536;
  const short* G1b = G1  + b*65536;
  const short* G2b = G2nf + b*65536;

  // ---- stage K (128 KB) into featS, SWZ[o][k]; stage fcb ----
  {
    int o = tid >> 1, half = (tid & 1) * 128;
    #pragma unroll
    for (int q = 0; q < 16; q++){
      int kk = half + q*8;
      bf16x8 v = *(const bf16x8*)(KA + o*256 + kk);
      *(bf16x8*)(featS + SWZ(o, kk*2)) = v;
    }
    if (tid < 256) fcbL[tid] = fcb[tid];
  }

  // rebuild assignment: thread -> (row nl 0..255, 16-k half)
  int nl = tid >> 1, rkk = (tid & 1) * 16;
  float cj = epsm1 * diag[b*256 + nl];

  // wave geometry (phase 1)
  int wro = (w >> 2) * 128;   // o-half
  int wn  = (w & 3) * 64;     // n-quarter
  int lr = lane & 15, lq = lane >> 4;
  int koff = lq * 8;

  // prefetch G1/G2 for k-step 0
  bf16x8 p1a = *(const bf16x8*)(G1b + nl*256 + rkk);
  bf16x8 p1b = *(const bf16x8*)(G1b + nl*256 + rkk + 8);
  bf16x8 p2a = *(const bf16x8*)(G2b + nl*256 + rkk);
  bf16x8 p2b = *(const bf16x8*)(G2b + nl*256 + rkk + 8);

  __syncthreads();   // K + fcb staged

  // ---------------- phase 1: feat = h1 @ K_h (shared h1s rebuild, acc[j_n][i_o]) ----------------
  f32x4 acc[4][8] = {};
  for (int t = 0; t < 8; t++){
    int k0 = t*32;
    {
      bf16x8 o1, o2;
      #pragma unroll
      for (int e = 0; e < 8; e++){
        float v = b2f(p1a[e]) + cj*b2f(p2a[e]) + fcbL[k0 + rkk + e];
        v = v > 0.f ? v : 0.01f*v;
        o1[e] = f2b(v);
      }
      #pragma unroll
      for (int e = 0; e < 8; e++){
        float v = b2f(p1b[e]) + cj*b2f(p2b[e]) + fcbL[k0 + rkk + 8 + e];
        v = v > 0.f ? v : 0.01f*v;
        o2[e] = f2b(v);
      }
      *(bf16x8*)&h1s[nl][rkk] = o1;
      *(bf16x8*)&h1s[nl][rkk + 8] = o2;
    }
    __syncthreads();
    if (t < 7){
      int kn = k0 + 32;
      p1a = *(const bf16x8*)(G1b + nl*256 + kn + rkk);
      p1b = *(const bf16x8*)(G1b + nl*256 + kn + rkk + 8);
      p2a = *(const bf16x8*)(G2b + nl*256 + kn + rkk);
      p2b = *(const bf16x8*)(G2b + nl*256 + kn + rkk + 8);
    }
    bf16x8 af[4];
    #pragma unroll
    for (int j = 0; j < 4; j++) af[j] = *(const bf16x8*)&h1s[wn + j*16 + lr][koff];
    #pragma unroll
    for (int i = 0; i < 8; i++){
      bf16x8 bfv = *(const bf16x8*)(featS + SWZ(wro + i*16 + lr, (k0 + koff)*2));
      #pragma unroll
      for (int j = 0; j < 4; j++)
        acc[j][i] = __builtin_amdgcn_mfma_f32_16x16x32_bf16(af[j], bfv, acc[j][i], 0, 0, 0);
    }
    __syncthreads();
  }

  // ---------------- epilogue: bias + vectorized feat^T stores + a_s/a_n partials ----------------
  float ps[4][4] = {}, pn[4][4] = {};
  #pragma unroll
  for (int i = 0; i < 8; i++){
    int od = wro + i*16 + lr;                       // o (lane-dim)
    float bi  = biases[h*256 + od];
    float wsv = atts[h*256 + od];
    float wnv = attn[h*256 + od];
    #pragma unroll
    for (int j = 0; j < 4; j++){
      short4v sv;
      #pragma unroll
      for (int r = 0; r < 4; r++){
        float fv = acc[j][i][r] + bi;
        sv[r] = f2b(fv);
        ps[j][r] += fv * wsv;
        pn[j][r] += fv * wnv;
      }
      *(short4v*)(featS + SWZ(od, (wn + j*16 + lq*4)*2) ) = sv;   // 8B store
    }
  }
  #pragma unroll
  for (int j = 0; j < 4; j++)
    #pragma unroll
    for (int r = 0; r < 4; r++){
      float s = ps[j][r], nv = pn[j][r];
      s += __shfl_xor(s, 1); s += __shfl_xor(s, 2); s += __shfl_xor(s, 4); s += __shfl_xor(s, 8);
      nv += __shfl_xor(nv, 1); nv += __shfl_xor(nv, 2); nv += __shfl_xor(nv, 4); nv += __shfl_xor(nv, 8);
      ps[j][r] = s; pn[j][r] = nv;
    }
  // h1s dead (last read before final phase-1 barrier) -> red + xbitsL overlays safe
  if (lr == 0){
    #pragma unroll
    for (int j = 0; j < 4; j++)
      #pragma unroll
      for (int r = 0; r < 4; r++){
        red_s[w][j*16 + lq*4 + r] = ps[j][r];
        red_n[w][j*16 + lq*4 + r] = pn[j][r];
      }
  }
  {
    const unsigned* xb = xbits + b*2048;
    #pragma unroll
    for (int q = 0; q < 4; q++) xbitsL[tid*4 + q] = xb[tid*4 + q];
  }
  __syncthreads();
  if (tid < 256){
    int q = tid >> 6, nn = tid & 63;
    asvL[tid] = red_s[q][nn] + red_s[q+4][nn] + attbv[h];
    anvL[tid] = red_n[q][nn] + red_n[q+4][nn];
  }
  __syncthreads();

  // ---------------- phase 2: wave-private softmax + PV, ZERO barriers ----------------
  // Wave w owns i-rows [w*32, w*32+32). Lane (lr,lq) holds P[row][kv = t*32+lq*8 .. +8]
  // for t=0..7 — exactly the MFMA B-fragment layout for all 8 k-steps.
  int wi = w * 32;
  bf16x8 bfp[2][8];
  #pragma unroll
  for (int sub = 0; sub < 2; sub++){
    int i = wi + sub*16 + lr;
    float as_i = asvL[i];
    float Lv[8][8];
    float mx = -3.0e38f;
    #pragma unroll
    for (int t = 0; t < 8; t++){
      unsigned bits = xbitsL[i*8 + t] >> (lq*8);
      #pragma unroll
      for (int e = 0; e < 8; e++){
        float s = as_i + anvL[t*32 + lq*8 + e];
        float el = s > 0.f ? s : (__expf(s) - 1.0f);
        float L = el + (((bits >> e) & 1u) ? 0.f : -1.0e10f);
        Lv[t][e] = L; mx = fmaxf(mx, L);
      }
    }
    mx = fmaxf(mx, __shfl_xor(mx, 16));
    mx = fmaxf(mx, __shfl_xor(mx, 32));
    float sum = 0.f;
    #pragma unroll
    for (int t = 0; t < 8; t++)
      #pragma unroll
      for (int e = 0; e < 8; e++){ float p = __expf(Lv[t][e] - mx); Lv[t][e] = p; sum += p; }
    sum += __shfl_xor(sum, 16);
    sum += __shfl_xor(sum, 32);
    float inv = 1.0f / sum;
    #pragma unroll
    for (int t = 0; t < 8; t++){
      bf16x8 pv;
      #pragma unroll
      for (int e = 0; e < 8; e++) pv[e] = f2b(Lv[t][e] * inv);
      bfp[sub][t] = pv;
    }
    if (h == 3){
      float* o2 = out2 + b*65536 + i*256 + lq*8;
      #pragma unroll
      for (int t = 0; t < 8; t++){
        f32x4 v0, v1;
        #pragma unroll
        for (int e = 0; e < 4; e++){ v0[e] = Lv[t][e]*inv; v1[e] = Lv[t][4+e]*inv; }
        *(f32x4*)(o2 + t*32) = v0;
        *(f32x4*)(o2 + t*32 + 4) = v1;
      }
    }
  }

  // PV: 16 o-tiles; afv reused for both i-subtiles; no barriers, waves drift freely.
  float* outb = out + (size_t)(b*256 + wi)*1024 + h*256;
  #pragma unroll 1
  for (int ot = 0; ot < 16; ot++){
    f32x4 a2[2] = {};
    #pragma unroll
    for (int t = 0; t < 8; t++){
      bf16x8 afv = *(const bf16x8*)(featS + SWZ(ot*16 + lr, (t*32 + lq*8)*2));
      a2[0] = __builtin_amdgcn_mfma_f32_16x16x32_bf16(afv, bfp[0][t], a2[0], 0, 0, 0);
      a2[1] = __builtin_amdgcn_mfma_f32_16x16x32_bf16(afv, bfp[1][t], a2[1], 0, 0, 0);
    }
    *(f32x4*)(outb + (size_t)(lr)*1024 + ot*16 + lq*4) = a2[0];
    *(f32x4*)(outb + (size_t)(16 + lr)*1024 + ot*16 + lq*4) = a2[1];
  }
}

extern "C" void kernel_launch(void* const* d_in, const int* in_sizes, int n_in,
                              void* d_out, int out_size, void* d_ws, size_t ws_size,
                              hipStream_t stream) {
  const float* atom   = (const float*)d_in[0];
  const float* x      = (const float*)d_in[1];
  const float* fc_w   = (const float*)d_in[2];
  const float* fc_b   = (const float*)d_in[3];
  const float* kers   = (const float*)d_in[4];
  const float* att_s  = (const float*)d_in[5];
  const float* att_n  = (const float*)d_in[6];
  const float* eps    = (const float*)d_in[7];
  const float* biases = (const float*)d_in[8];
  const float* att_b  = (const float*)d_in[9];

  // ws layout (~34 MB)
  char* w = (char*)d_ws;
  short* WT      = (short*)(w);                      // [0,        131072)
  short* KhT     = (short*)(w + 131072);             // [131072,   655360)
  float* diag    = (float*)(w + 655360);             // [655360,   786432)
  unsigned* xbits= (unsigned*)(w + 786432);          // [786432,  1835008)
  short* G2nf    = (short*)(w + 1835008);            // [1835008, 18612224)
  short* G1      = (short*)(w + 18612224);           // [18612224, 35389440)

  float* out  = (float*)d_out;
  float* out2 = out + 33554432;  // B*N*H*D floats

  ktrans<<<dim3(8, 8, 5), 256, 0, stream>>>(fc_w, kers, WT, KhT);
  kG12<<<dim3(256), 512, 0, stream>>>(WT, atom, x, G2nf, G1, xbits, diag);
  kHead<<<dim3(512), 512, 0, stream>>>(KhT, G1, G2nf, diag, fc_b, eps,
                                       biases, att_s, att_n, att_b, xbits, out, out2);
}